// Round 4
// baseline (157.265 us; speedup 1.0000x reference)
//
#include <hip/hip_runtime.h>
#include <hip/hip_bf16.h>
#include <stdint.h>

#define EPSF 1e-5f

typedef short    short8v __attribute__((ext_vector_type(8)));
typedef float    f32x4   __attribute__((ext_vector_type(4)));
typedef uint32_t u32x4   __attribute__((ext_vector_type(4)));

// dims: T=4, B=16, C=256, H*W=256, Hid=1024, E=8, TOPK=2 -> 32 slots
// x layout (T,B,C,H,W): idx = ((t*16+b)*256+c)*256 + hw ; t-stride = 1048576

static __device__ __forceinline__ short bf16bits(float f) {
    __hip_bfloat16 h = __float2bfloat16(f);
    return *reinterpret_cast<short*>(&h);
}

// unpack 8 spike bits -> 8 bf16 (0.0 / 1.0) entirely in registers
static __device__ __forceinline__ short8v unpack8(uint32_t by) {
    uint32_t lo = ((by & 0xFu) * 0x00204081u) & 0x01010101u;
    uint32_t hi = ((by >> 4)   * 0x00204081u) & 0x01010101u;
    union { short8v s; uint32_t u[4]; } r;
    r.u[0] = __builtin_amdgcn_perm(0u, lo, 0x04010400u) * 0x3F80u;
    r.u[1] = __builtin_amdgcn_perm(0u, lo, 0x04030402u) * 0x3F80u;
    r.u[2] = __builtin_amdgcn_perm(0u, hi, 0x04010400u) * 0x3F80u;
    r.u[3] = __builtin_amdgcn_perm(0u, hi, 0x04030402u) * 0x3F80u;
    return r.s;
}

typedef const __attribute__((address_space(1))) char* gas_p;
typedef __attribute__((address_space(3))) char* las_p;
static __device__ __forceinline__ void gl16(const void* g, void* l) {
    __builtin_amdgcn_global_load_lds((gas_p)g, (las_p)l, 16, 0, 0);
}
#define SBAR()   __builtin_amdgcn_s_barrier()
#define SCHED0() __builtin_amdgcn_sched_barrier(0)

// ---------------- prep: all-8 LIF + xbar (x read ONCE), weight convert+tile+swizzle, BN fold --------
// s1p[e][b][ks(8)][row(1024)] u32 (row = hw*4+t)                              4 MiB
// w1c[e][nt4][ks8][hilo2][n256][32 sh], unit u=(cl>>3)^(n&3)^((n>>2)&3)       8 MiB
// w2t[e][nt4][ks16][n64][64 sh],        unit u=(kl>>3)^(n&7)                  4 MiB
__global__ void k_prep(const float* __restrict__ w1, const float* __restrict__ w2,
                       const float* __restrict__ x,
                       const float* __restrict__ b1, const float* __restrict__ g1, const float* __restrict__ be1,
                       const float* __restrict__ m1, const float* __restrict__ v1,
                       const float* __restrict__ b2, const float* __restrict__ g2, const float* __restrict__ be2,
                       const float* __restrict__ m2, const float* __restrict__ v2,
                       short* __restrict__ w1c, short* __restrict__ w2t,
                       float* __restrict__ sc1, float* __restrict__ sh1,
                       float* __restrict__ sc2, float* __restrict__ sh2,
                       float* __restrict__ xbar, uint32_t* __restrict__ s1p) {
    int blk = blockIdx.x;
    if (blk < 128) {
        // all-8-expert LIF1 + xbar partial sums; block = (b, wq) over 32 c's
        __shared__ float P[4][33];
        int b = blk >> 3, wq = blk & 7;
        int hw = threadIdx.x;              // 256
        int wave = hw >> 6, lane = hw & 63;
        uint32_t we[8][4];
        #pragma unroll
        for (int e = 0; e < 8; ++e)
            #pragma unroll
            for (int t = 0; t < 4; ++t) we[e][t] = 0;
        const float* xb = x + (size_t)b * 65536 + hw;
        for (int j = 0; j < 32; ++j) {
            const float* xp = xb + (size_t)(wq * 32 + j) * 256;
            float x0 = xp[0], x1 = xp[1048576], x2 = xp[2097152], x3 = xp[3145728];
            float sx = x0 + x1 + x2 + x3;
            #pragma unroll
            for (int off = 32; off; off >>= 1) sx += __shfl_down(sx, off);
            if (lane == 0) P[wave][j] = sx;
            #pragma unroll
            for (int e = 0; e < 8; ++e) {
                float tau = 1.5f + e * (2.5f / 7.0f);
                float v;
                v = x0 / tau;           if (v >= 1.f) { we[e][0] |= 1u << j; v = 0.f; }
                v = v + (x1 - v) / tau; if (v >= 1.f) { we[e][1] |= 1u << j; v = 0.f; }
                v = v + (x2 - v) / tau; if (v >= 1.f) { we[e][2] |= 1u << j; v = 0.f; }
                v = v + (x3 - v) / tau; if (v >= 1.f) { we[e][3] |= 1u << j; }
            }
        }
        __syncthreads();
        if (hw < 32)
            xbar[b * 256 + wq * 32 + hw] =
                (P[0][hw] + P[1][hw] + P[2][hw] + P[3][hw]) * (1.0f / 1024.0f);
        #pragma unroll
        for (int e = 0; e < 8; ++e) {
            u32x4 wv = (u32x4){we[e][0], we[e][1], we[e][2], we[e][3]};
            *(u32x4*)&s1p[(size_t)((e * 16 + b) * 8 + wq) * 1024 + hw * 4] = wv;
        }
    } else if (blk < 8320) {
        int idx = (blk - 128) * 256 + threadIdx.x;
        {   // w1 hi/lo split, tiled+swizzled
            float f = w1[idx];
            __hip_bfloat16 h = __float2bfloat16(f);
            short hb = *reinterpret_cast<short*>(&h);
            float hf = __bfloat162float(h);
            int e = idx >> 18, o = (idx >> 8) & 1023, c = idx & 255;
            int nt = o >> 8, n = o & 255, ks = c >> 5, cl = c & 31;
            int u = ((cl >> 3) ^ (n & 3) ^ ((n >> 2) & 3)) & 3, j = cl & 7;
            size_t base = (((size_t)((e * 4 + nt) * 8 + ks) * 2) * 256 + n) * 32 + u * 8 + j;
            w1c[base] = hb;                      // hi
            w1c[base + 8192] = bf16bits(f - hf); // lo plane (+256*32)
        }
        {   // w2 bf16, tiled+swizzled
            float f = w2[idx];
            int e = idx >> 18, co = (idx >> 10) & 255, k = idx & 1023;
            int nt = co >> 6, n = co & 63, ks = k >> 6, kl = k & 63;
            int u = (kl >> 3) ^ (n & 7), j = kl & 7;
            size_t off = (((size_t)((e * 4 + nt) * 16 + ks) * 64) + n) * 64 + u * 8 + j;
            w2t[off] = bf16bits(f);
        }
    } else {
        int idx = (blk - 8320) * 256 + threadIdx.x;   // 0..8191
        {
            float s = g1[idx] / sqrtf(v1[idx] + EPSF);
            sc1[idx] = s;
            sh1[idx] = be1[idx] + s * (b1[idx] - m1[idx]);
        }
        if (idx < 2048) {
            float s = g2[idx] / sqrtf(v2[idx] + EPSF);
            sc2[idx] = s;
            sh2[idx] = be2[idx] + s * (b2[idx] - m2[idx]);
        }
    }
}

// ---------------- router stage 2: logits -> top-2 -> expert-sorted 32 slots ----------------
__global__ void k_r2(const float* __restrict__ xbar, const float* __restrict__ rw, const float* __restrict__ rb,
                     const float* __restrict__ rg, const float* __restrict__ rbt,
                     const float* __restrict__ rm, const float* __restrict__ rv,
                     int* __restrict__ slotE, float* __restrict__ slotW,
                     int* __restrict__ slotB, int* __restrict__ bslot) {
    __shared__ float L[16][8];
    __shared__ int   tE[32];
    __shared__ float tW[32];
    int tid = threadIdx.x; // 128
    if (tid < 128) {
        int b = tid >> 3, e = tid & 7;
        float s = 0.f;
        for (int c = 0; c < 256; ++c) s += xbar[b * 256 + c] * rw[e * 256 + c];
        s += rb[e];
        L[b][e] = rg[e] * (s - rm[e]) / sqrtf(rv[e] + EPSF) + rbt[e];
    }
    __syncthreads();
    if (tid < 16) {
        int b = tid;
        float l[8];
        #pragma unroll
        for (int e = 0; e < 8; ++e) l[e] = L[b][e];
        int i1 = 0;
        for (int e = 1; e < 8; ++e) if (l[e] > l[i1]) i1 = e;
        int i2 = (i1 == 0) ? 1 : 0;
        for (int e = 0; e < 8; ++e) { if (e == i1) continue; if (l[e] > l[i2]) i2 = e; }
        float d = l[i2] - l[i1];
        float ed = expf(d);
        tE[b * 2]     = i1; tW[b * 2]     = 1.f / (1.f + ed);
        tE[b * 2 + 1] = i2; tW[b * 2 + 1] = ed / (1.f + ed);
    }
    __syncthreads();
    if (tid == 0) {
        int pos = 0;
        for (int e = 0; e < 8; ++e)
            for (int i = 0; i < 32; ++i)
                if (tE[i] == e) {
                    slotE[pos] = e; slotW[pos] = tW[i]; slotB[pos] = i >> 1;
                    bslot[i] = pos; ++pos;
                }
    }
}

// stage one 32KB w1 (ks) tile: hi 16KB + lo 16KB, 512 thr x 4 gl16
static __device__ __forceinline__ void stage_g1(const char* wt, char* dst, int wid, int lane) {
    #pragma unroll
    for (int i = 0; i < 4; ++i)
        gl16(wt + i * 8192 + (wid * 64 + lane) * 16, dst + i * 8192 + wid * 1024);
}

// ================= GEMM1: spikes x w1(hi/lo) + BN1 + LIF2 -> s2p =================
// block tile M=256 x N=256, 8 phases K=32 (hi+lo each). 512 thr = 8 waves (2m x 4n),
// wave-tile 128x64 (mf=8, nf=4). A per-lane from global; single barrier/phase, vmcnt(8).
__global__ __launch_bounds__(512, 2) void k_g1(const uint32_t* __restrict__ s1p,
                                               const short* __restrict__ w1c,
                                               const float* __restrict__ sc1, const float* __restrict__ sh1,
                                               const int* __restrict__ slotE, const int* __restrict__ slotB,
                                               uint32_t* __restrict__ s2p) {
    __shared__ __align__(16) char SM[65536];   // 2 x 32KB B-buffers; epilogue aliases

    const int tid = threadIdx.x;
    const int wg = ((blockIdx.x & 7) << 6) | (blockIdx.x >> 3);   // XCD swizzle (512 % 8 == 0)
    const int slot = wg & 31, mt = (wg >> 5) & 3, nt = (wg >> 7) & 3;
    const int e = slotE[slot], b = slotB[slot];
    const int lane = tid & 63, wid = tid >> 6;
    const int wm = wid & 1, wn = wid >> 1;
    const int l15 = lane & 15, lhi = lane >> 4;

    f32x4 acc[8][4];
    #pragma unroll
    for (int i = 0; i < 8; ++i)
        #pragma unroll
        for (int j = 0; j < 4; ++j) acc[i][j] = (f32x4){0.f, 0.f, 0.f, 0.f};

    const char* wbase = (const char*)(w1c + (size_t)((e * 4 + nt) * 8) * 16384);   // 32KB per ks
    const uint32_t* abase = s1p + (size_t)((e * 16 + b) * 8) * 1024 + (mt * 256 + wm * 128 + l15);

    uint32_t awA[8], awB[8];
    // prologue issue order: A(0) 8, S(0) 4, A(1) 8
    #pragma unroll
    for (int mf = 0; mf < 8; ++mf) awA[mf] = abase[mf * 16];
    SCHED0();
    stage_g1(wbase, SM, wid, lane);
    SCHED0();
    #pragma unroll
    for (int mf = 0; mf < 8; ++mf) awB[mf] = abase[1024 + mf * 16];
    SCHED0();

    #pragma unroll
    for (int p = 0; p < 8; ++p) {
        if (p < 7) asm volatile("s_waitcnt vmcnt(8)" ::: "memory");
        else       asm volatile("s_waitcnt vmcnt(0)" ::: "memory");
        SBAR();
        const short* Bb = (const short*)(SM + (p & 1) * 32768);
        short8v bh[4], bl[4];
        #pragma unroll
        for (int nf = 0; nf < 4; ++nf) {
            int n = wn * 64 + nf * 16 + l15;
            int u = (lhi ^ (n & 3) ^ ((n >> 2) & 3)) & 3;
            bh[nf] = *(const short8v*)&Bb[n * 32 + u * 8];
            bl[nf] = *(const short8v*)&Bb[8192 + n * 32 + u * 8];
        }
        uint32_t awc[8];
        #pragma unroll
        for (int mf = 0; mf < 8; ++mf) awc[mf] = (p & 1) ? awB[mf] : awA[mf];
        SCHED0();
        if (p < 7) stage_g1(wbase + (p + 1) * 32768, SM + ((p + 1) & 1) * 32768, wid, lane);
        SCHED0();
        if (p < 6) {
            #pragma unroll
            for (int mf = 0; mf < 8; ++mf) {
                uint32_t v = abase[(p + 2) * 1024 + mf * 16];
                if (p & 1) awB[mf] = v; else awA[mf] = v;
            }
        }
        SCHED0();
        __builtin_amdgcn_s_setprio(1);
        #pragma unroll
        for (int mf = 0; mf < 8; ++mf) {
            short8v af = unpack8((awc[mf] >> (lhi * 8)) & 0xffu);
            #pragma unroll
            for (int nf = 0; nf < 4; ++nf)
                acc[mf][nf] = __builtin_amdgcn_mfma_f32_16x16x32_bf16(af, bh[nf], acc[mf][nf], 0, 0, 0);
            #pragma unroll
            for (int nf = 0; nf < 4; ++nf)
                acc[mf][nf] = __builtin_amdgcn_mfma_f32_16x16x32_bf16(af, bl[nf], acc[mf][nf], 0, 0, 0);
        }
        __builtin_amdgcn_s_setprio(0);
    }

    __syncthreads();
    // epilogue: BN1 + LIF2 (4 t in each lane's acc regs) + ballot-pack
    unsigned short (*SPK)[16] = (unsigned short(*)[16])SM;
    const float tau = 1.5f + e * (2.5f / 7.0f);
    #pragma unroll
    for (int mf = 0; mf < 8; ++mf) {
        #pragma unroll
        for (int nf = 0; nf < 4; ++nf) {
            int o = nt * 256 + wn * 64 + nf * 16 + l15;
            float sc = sc1[e * 1024 + o], sh = sh1[e * 1024 + o];
            float v = 0.f;
            #pragma unroll
            for (int t = 0; t < 4; ++t) {
                float bnv = sc * acc[mf][nf][t] + sh;
                v = v + (bnv - v) / tau;
                bool sp = (v >= 1.f);
                unsigned long long bal = __ballot(sp);
                if (sp) v = 0.f;
                if (l15 == 0)
                    SPK[wm * 128 + mf * 16 + lhi * 4 + t][wn * 4 + nf] =
                        (unsigned short)((bal >> (lhi * 16)) & 0xFFFFull);
            }
        }
    }
    __syncthreads();
    if (tid < 256) {
        int row = tid;
        #pragma unroll
        for (int w = 0; w < 8; ++w) {
            uint32_t word = (uint32_t)SPK[row][2 * w] | ((uint32_t)SPK[row][2 * w + 1] << 16);
            s2p[(size_t)(slot * 32 + nt * 8 + w) * 1024 + mt * 256 + row] = word;
        }
    }
}

// stage 16KB: rank0 tile 8KB + rank1 tile 8KB, 256 thr x 4 gl16
static __device__ __forceinline__ void stage_g2(const char* w0, const char* w1, char* dst, int wid, int lane) {
    gl16(w0 + (wid * 64 + lane) * 16, dst + wid * 1024);
    gl16(w0 + 4096 + (wid * 64 + lane) * 16, dst + 4096 + wid * 1024);
    gl16(w1 + (wid * 64 + lane) * 16, dst + 8192 + wid * 1024);
    gl16(w1 + 4096 + (wid * 64 + lane) * 16, dst + 12288 + wid * 1024);
}

// ================= GEMM2: spikes2 x w2, both ranks fused, + BN2 + combine =================
// block tile M=256 x N=64, 16 phases K=64. 256 thr = 4 waves (2 rank x 2 m),
// wave-tile 128x64 (mf=8, nf=4). A per-lane from global; single barrier/phase, vmcnt(16).
__global__ __launch_bounds__(256, 2) void k_g2(const uint32_t* __restrict__ s2p,
                                               const short* __restrict__ w2t,
                                               const float* __restrict__ sc2, const float* __restrict__ sh2,
                                               const int* __restrict__ slotE, const float* __restrict__ slotW,
                                               const int* __restrict__ bslot,
                                               const float* __restrict__ x, float* __restrict__ out) {
    __shared__ __align__(16) char SM[33280];   // 2 x 16KB buffers; Y(33280) aliases

    const int tid = threadIdx.x;
    const int wg = ((blockIdx.x & 7) << 5) | (blockIdx.x >> 3);   // XCD swizzle (256 % 8 == 0)
    const int b = wg & 15, mt = (wg >> 4) & 3, nt = (wg >> 6) & 3;
    const int lane = tid & 63, wid = tid >> 6;
    const int rank = wid >> 1, wm = wid & 1;
    const int l15 = lane & 15, lhi = lane >> 4;

    const int slot = bslot[b * 2 + rank];
    const int e = slotE[slot];
    const float wgt = slotW[slot];
    const int e0 = slotE[bslot[b * 2]], e1 = slotE[bslot[b * 2 + 1]];

    f32x4 acc[8][4];
    #pragma unroll
    for (int i = 0; i < 8; ++i)
        #pragma unroll
        for (int j = 0; j < 4; ++j) acc[i][j] = (f32x4){0.f, 0.f, 0.f, 0.f};

    const char* wb0 = (const char*)(w2t + (size_t)((e0 * 4 + nt) * 16) * 4096);  // 8KB per ks
    const char* wb1 = (const char*)(w2t + (size_t)((e1 * 4 + nt) * 16) * 4096);
    const uint32_t* abase = s2p + (size_t)slot * 32768 + (mt * 256 + wm * 128 + l15);

    uint32_t awA[16], awB[16];
    // prologue issue order: A(0) 16, S(0) 4, A(1) 16
    #pragma unroll
    for (int mf = 0; mf < 8; ++mf) {
        awA[mf * 2]     = abase[mf * 16];
        awA[mf * 2 + 1] = abase[1024 + mf * 16];
    }
    SCHED0();
    stage_g2(wb0, wb1, SM, wid, lane);
    SCHED0();
    #pragma unroll
    for (int mf = 0; mf < 8; ++mf) {
        awB[mf * 2]     = abase[2048 + mf * 16];
        awB[mf * 2 + 1] = abase[3072 + mf * 16];
    }
    SCHED0();

    #pragma unroll
    for (int p = 0; p < 16; ++p) {
        if (p < 15) asm volatile("s_waitcnt vmcnt(16)" ::: "memory");
        else        asm volatile("s_waitcnt vmcnt(0)" ::: "memory");
        SBAR();
        const short* Bb = (const short*)(SM + (p & 1) * 16384 + rank * 8192);
        short8v bq[2][4];
        #pragma unroll
        for (int kf = 0; kf < 2; ++kf)
            #pragma unroll
            for (int nf = 0; nf < 4; ++nf) {
                int n = nf * 16 + l15;
                int u = (kf * 4 + lhi) ^ (n & 7);
                bq[kf][nf] = *(const short8v*)&Bb[n * 64 + u * 8];
            }
        uint32_t awc[16];
        #pragma unroll
        for (int i = 0; i < 16; ++i) awc[i] = (p & 1) ? awB[i] : awA[i];
        SCHED0();
        if (p < 15) stage_g2(wb0 + (p + 1) * 8192, wb1 + (p + 1) * 8192,
                             SM + ((p + 1) & 1) * 16384, wid, lane);
        SCHED0();
        if (p < 14) {
            #pragma unroll
            for (int mf = 0; mf < 8; ++mf) {
                uint32_t v0 = abase[(p + 2) * 2048 + mf * 16];
                uint32_t v1 = abase[(p + 2) * 2048 + 1024 + mf * 16];
                if (p & 1) { awB[mf * 2] = v0; awB[mf * 2 + 1] = v1; }
                else       { awA[mf * 2] = v0; awA[mf * 2 + 1] = v1; }
            }
        }
        SCHED0();
        __builtin_amdgcn_s_setprio(1);
        #pragma unroll
        for (int mf = 0; mf < 8; ++mf) {
            #pragma unroll
            for (int kf = 0; kf < 2; ++kf) {
                short8v af = unpack8((awc[mf * 2 + kf] >> (lhi * 8)) & 0xffu);
                #pragma unroll
                for (int nf = 0; nf < 4; ++nf)
                    acc[mf][nf] = __builtin_amdgcn_mfma_f32_16x16x32_bf16(af, bq[kf][nf], acc[mf][nf], 0, 0, 0);
            }
        }
        __builtin_amdgcn_s_setprio(0);
    }

    __syncthreads();
    // epilogue: rank1 writes wgt*y to LDS Y, rank0 adds, stream out = x + Y (two 32-hw chunks)
    float (*Y)[32][65] = (float(*)[32][65])SM;
    #pragma unroll
    for (int wmsel = 0; wmsel < 2; ++wmsel) {
        if (rank == 1 && wm == wmsel) {
            #pragma unroll
            for (int mf = 0; mf < 8; ++mf)
                #pragma unroll
                for (int nf = 0; nf < 4; ++nf) {
                    int cl = nf * 16 + l15;
                    int cg = nt * 64 + cl;
                    float sc = sc2[e * 256 + cg], sh = sh2[e * 256 + cg];
                    int hwl = mf * 4 + lhi;
                    #pragma unroll
                    for (int t = 0; t < 4; ++t)
                        Y[t][hwl][cl] = wgt * (sc * acc[mf][nf][t] + sh);
                }
        }
        __syncthreads();
        if (rank == 0 && wm == wmsel) {
            #pragma unroll
            for (int mf = 0; mf < 8; ++mf)
                #pragma unroll
                for (int nf = 0; nf < 4; ++nf) {
                    int cl = nf * 16 + l15;
                    int cg = nt * 64 + cl;
                    float sc = sc2[e * 256 + cg], sh = sh2[e * 256 + cg];
                    int hwl = mf * 4 + lhi;
                    #pragma unroll
                    for (int t = 0; t < 4; ++t)
                        Y[t][hwl][cl] += wgt * (sc * acc[mf][nf][t] + sh);
                }
        }
        __syncthreads();
        #pragma unroll
        for (int it = 0; it < 32; ++it) {
            int p2 = it * 256 + tid;
            int hwi = p2 & 31, t = (p2 >> 5) & 3, cl = p2 >> 7;
            int hwg = mt * 64 + wmsel * 32 + hwi;
            size_t oidx = ((size_t)(t * 16 + b) * 256 + nt * 64 + cl) * 256 + hwg;
            out[oidx] = x[oidx] + Y[t][hwi][cl];
        }
        __syncthreads();
    }
}

extern "C" void kernel_launch(void* const* d_in, const int* in_sizes, int n_in,
                              void* d_out, int out_size, void* d_ws, size_t ws_size,
                              hipStream_t stream) {
    const float* x   = (const float*)d_in[0];
    const float* rw  = (const float*)d_in[1];
    const float* rb  = (const float*)d_in[2];
    const float* rg  = (const float*)d_in[3];
    const float* rbt = (const float*)d_in[4];
    const float* rm  = (const float*)d_in[5];
    const float* rv  = (const float*)d_in[6];
    const float* w1  = (const float*)d_in[7];
    const float* b1  = (const float*)d_in[8];
    const float* g1  = (const float*)d_in[9];
    const float* be1 = (const float*)d_in[10];
    const float* m1  = (const float*)d_in[11];
    const float* v1  = (const float*)d_in[12];
    const float* w2  = (const float*)d_in[13];
    const float* b2  = (const float*)d_in[14];
    const float* g2  = (const float*)d_in[15];
    const float* be2 = (const float*)d_in[16];
    const float* m2  = (const float*)d_in[17];
    const float* v2  = (const float*)d_in[18];
    float* out = (float*)d_out;

    char* ws = (char*)d_ws;
    short*    w1c   = (short*)(ws);                    // 8 MiB
    short*    w2t   = (short*)(ws + 8388608);          // 4 MiB
    float*    sc1   = (float*)(ws + 12582912);         // 32 KiB
    float*    sh1   = (float*)(ws + 12615680);         // 32 KiB
    float*    sc2   = (float*)(ws + 12648448);         // 8 KiB
    float*    sh2   = (float*)(ws + 12656640);         // 8 KiB
    float*    xbar  = (float*)(ws + 12664832);         // 16 KiB
    int*      slotE = (int*)  (ws + 12681216);         // 128 B
    float*    slotW = (float*)(ws + 12681344);         // 128 B
    int*      slotB = (int*)  (ws + 12681472);         // 128 B
    int*      bslot = (int*)  (ws + 12681600);         // 128 B
    uint32_t* s1p   = (uint32_t*)(ws + 12681728);      // 4 MiB
    uint32_t* s2p   = (uint32_t*)(ws + 16876032);      // 4 MiB (total ~20.1 MiB)

    k_prep<<<8352, 256, 0, stream>>>(w1, w2, x, b1, g1, be1, m1, v1, b2, g2, be2, m2, v2,
                                     w1c, w2t, sc1, sh1, sc2, sh2, xbar, s1p);
    k_r2  <<<1, 128, 0, stream>>>(xbar, rw, rb, rg, rbt, rm, rv, slotE, slotW, slotB, bslot);
    k_g1  <<<512, 512, 0, stream>>>(s1p, w1c, sc1, sh1, slotE, slotB, s2p);
    k_g2  <<<256, 256, 0, stream>>>(s2p, w2t, sc2, sh2, slotE, slotW, bslot, x, out);
}

// Round 5
// 125.113 us; speedup vs baseline: 1.2570x; 1.2570x over previous
//
#include <hip/hip_runtime.h>
#include <hip/hip_bf16.h>
#include <stdint.h>

#define EPSF 1e-5f

typedef short    short8v __attribute__((ext_vector_type(8)));
typedef float    f32x4   __attribute__((ext_vector_type(4)));
typedef uint32_t u32x4   __attribute__((ext_vector_type(4)));

// dims: T=4, B=16, C=256, H*W=256, Hid=1024, E=8, TOPK=2 -> 32 slots
// x layout (T,B,C,H,W): idx = ((t*16+b)*256+c)*256 + hw ; t-stride = 1048576

static __device__ __forceinline__ short bf16bits(float f) {
    __hip_bfloat16 h = __float2bfloat16(f);
    return *reinterpret_cast<short*>(&h);
}

// unpack 8 spike bits -> 8 bf16 (0.0 / 1.0) entirely in registers
static __device__ __forceinline__ short8v unpack8(uint32_t by) {
    uint32_t lo = ((by & 0xFu) * 0x00204081u) & 0x01010101u;
    uint32_t hi = ((by >> 4)   * 0x00204081u) & 0x01010101u;
    union { short8v s; uint32_t u[4]; } r;
    r.u[0] = __builtin_amdgcn_perm(0u, lo, 0x04010400u) * 0x3F80u;
    r.u[1] = __builtin_amdgcn_perm(0u, lo, 0x04030402u) * 0x3F80u;
    r.u[2] = __builtin_amdgcn_perm(0u, hi, 0x04010400u) * 0x3F80u;
    r.u[3] = __builtin_amdgcn_perm(0u, hi, 0x04030402u) * 0x3F80u;
    return r.s;
}

typedef const __attribute__((address_space(1))) char* gas_p;
typedef __attribute__((address_space(3))) char* las_p;
static __device__ __forceinline__ void gl16(const void* g, void* l) {
    __builtin_amdgcn_global_load_lds((gas_p)g, (las_p)l, 16, 0, 0);
}
#define SBAR()   __builtin_amdgcn_s_barrier()
#define SCHED0() __builtin_amdgcn_sched_barrier(0)

// ---------------- prep: weight convert+tile+swizzle, BN fold, router stage-1 (NO LIF) --------
// w1c[e][nt4][ks8][hilo2][n256][32 sh], unit u=(cl>>3)^(n&3)^((n>>2)&3)       8 MiB
// w2t[e][nt4][ks16][n64][64 sh],        unit u=(kl>>3)^(n&7)                  4 MiB
__global__ void k_prep(const float* __restrict__ w1, const float* __restrict__ w2,
                       const float* __restrict__ x,
                       const float* __restrict__ b1, const float* __restrict__ g1, const float* __restrict__ be1,
                       const float* __restrict__ m1, const float* __restrict__ v1,
                       const float* __restrict__ b2, const float* __restrict__ g2, const float* __restrict__ be2,
                       const float* __restrict__ m2, const float* __restrict__ v2,
                       short* __restrict__ w1c, short* __restrict__ w2t,
                       float* __restrict__ sc1, float* __restrict__ sh1,
                       float* __restrict__ sc2, float* __restrict__ sh2,
                       float* __restrict__ xbar) {
    int blk = blockIdx.x;
    if (blk < 8192) {
        int idx = blk * 256 + threadIdx.x;
        {   // w1 hi/lo split, tiled+swizzled
            float f = w1[idx];
            __hip_bfloat16 h = __float2bfloat16(f);
            short hb = *reinterpret_cast<short*>(&h);
            float hf = __bfloat162float(h);
            int e = idx >> 18, o = (idx >> 8) & 1023, c = idx & 255;
            int nt = o >> 8, n = o & 255, ks = c >> 5, cl = c & 31;
            int u = ((cl >> 3) ^ (n & 3) ^ ((n >> 2) & 3)) & 3, j = cl & 7;
            size_t base = (((size_t)((e * 4 + nt) * 8 + ks) * 2) * 256 + n) * 32 + u * 8 + j;
            w1c[base] = hb;                      // hi
            w1c[base + 8192] = bf16bits(f - hf); // lo plane (+256*32)
        }
        {   // w2 bf16, tiled+swizzled
            float f = w2[idx];
            int e = idx >> 18, co = (idx >> 10) & 255, k = idx & 1023;
            int nt = co >> 6, n = co & 63, ks = k >> 6, kl = k & 63;
            int u = (kl >> 3) ^ (n & 7), j = kl & 7;
            size_t off = (((size_t)((e * 4 + nt) * 16 + ks) * 64) + n) * 64 + u * 8 + j;
            w2t[off] = bf16bits(f);
        }
    } else if (blk < 8224) {
        int idx = (blk - 8192) * 256 + threadIdx.x;   // 0..8191
        {
            float s = g1[idx] / sqrtf(v1[idx] + EPSF);
            sc1[idx] = s;
            sh1[idx] = be1[idx] + s * (b1[idx] - m1[idx]);
        }
        if (idx < 2048) {
            float s = g2[idx] / sqrtf(v2[idx] + EPSF);
            sc2[idx] = s;
            sh2[idx] = be2[idx] + s * (b2[idx] - m2[idx]);
        }
    } else {
        // router stage 1: xbar[b*256+c] = mean over (T,H,W); 4 waves/block, 1 bc each
        int wid = threadIdx.x >> 6, lane = threadIdx.x & 63;
        int bc = (blk - 8224) * 4 + wid;
        const float* xp = x + (size_t)bc * 256;
        float s = 0.f;
        #pragma unroll
        for (int t = 0; t < 4; ++t)
            #pragma unroll
            for (int i = 0; i < 4; ++i)
                s += xp[(size_t)t * 1048576 + i * 64 + lane];
        #pragma unroll
        for (int off = 32; off; off >>= 1) s += __shfl_down(s, off);
        if (lane == 0) xbar[bc] = s * (1.0f / 1024.0f);
    }
}

// ---------------- router stage 2: logits -> top-2 -> expert-sorted 32 slots ----------------
__global__ void k_r2(const float* __restrict__ xbar, const float* __restrict__ rw, const float* __restrict__ rb,
                     const float* __restrict__ rg, const float* __restrict__ rbt,
                     const float* __restrict__ rm, const float* __restrict__ rv,
                     int* __restrict__ slotE, float* __restrict__ slotW, int* __restrict__ bslot) {
    __shared__ float L[16][8];
    __shared__ int   tE[32];
    __shared__ float tW[32];
    int tid = threadIdx.x; // 128
    if (tid < 128) {
        int b = tid >> 3, e = tid & 7;
        float s = 0.f;
        for (int c = 0; c < 256; ++c) s += xbar[b * 256 + c] * rw[e * 256 + c];
        s += rb[e];
        L[b][e] = rg[e] * (s - rm[e]) / sqrtf(rv[e] + EPSF) + rbt[e];
    }
    __syncthreads();
    if (tid < 16) {
        int b = tid;
        float l[8];
        #pragma unroll
        for (int e = 0; e < 8; ++e) l[e] = L[b][e];
        int i1 = 0;
        for (int e = 1; e < 8; ++e) if (l[e] > l[i1]) i1 = e;
        int i2 = (i1 == 0) ? 1 : 0;
        for (int e = 0; e < 8; ++e) { if (e == i1) continue; if (l[e] > l[i2]) i2 = e; }
        float d = l[i2] - l[i1];
        float ed = expf(d);
        tE[b * 2]     = i1; tW[b * 2]     = 1.f / (1.f + ed);
        tE[b * 2 + 1] = i2; tW[b * 2 + 1] = ed / (1.f + ed);
    }
    __syncthreads();
    if (tid == 0) {
        int pos = 0;
        for (int e = 0; e < 8; ++e)
            for (int i = 0; i < 32; ++i)
                if (tE[i] == e) {
                    slotE[pos] = e; slotW[pos] = tW[i];
                    bslot[i] = pos; ++pos;
                }
    }
}

// ---------------- LIF1: 32 routed slots, x read once, ILP-heavy ----------------
// grid (16 b, 8 wq, 4 hwq) x 64 thr. s1p[slot][ks(8)][row(1024)] u32, row = hw*4+t.
__global__ __launch_bounds__(64) void k_lif1(const float* __restrict__ x, const int* __restrict__ slotE,
                                             const int* __restrict__ bslot, uint32_t* __restrict__ s1p) {
    const int b = blockIdx.x, wq = blockIdx.y, hwq = blockIdx.z;
    const int s0 = bslot[b * 2], s1v = bslot[b * 2 + 1];
    const float ta = 1.5f + slotE[s0]  * (2.5f / 7.0f);
    const float tb = 1.5f + slotE[s1v] * (2.5f / 7.0f);
    const int lane = threadIdx.x;
    const int hw = hwq * 64 + lane;
    uint32_t wa[4] = {0, 0, 0, 0}, wb[4] = {0, 0, 0, 0};
    const float* xb = x + (size_t)b * 65536 + (size_t)wq * 8192 + hw;
    #pragma unroll
    for (int j0 = 0; j0 < 32; j0 += 8) {
        float xv[8][4];
        #pragma unroll
        for (int j = 0; j < 8; ++j)
            #pragma unroll
            for (int t = 0; t < 4; ++t)
                xv[j][t] = xb[(size_t)t * 1048576 + (size_t)(j0 + j) * 256];
        #pragma unroll
        for (int j = 0; j < 8; ++j) {
            const uint32_t m = 1u << (j0 + j);
            float v;
            v = xv[j][0] / ta;          if (v >= 1.f) { wa[0] |= m; v = 0.f; }
            v = v + (xv[j][1] - v) / ta; if (v >= 1.f) { wa[1] |= m; v = 0.f; }
            v = v + (xv[j][2] - v) / ta; if (v >= 1.f) { wa[2] |= m; v = 0.f; }
            v = v + (xv[j][3] - v) / ta; if (v >= 1.f) { wa[3] |= m; }
            v = xv[j][0] / tb;          if (v >= 1.f) { wb[0] |= m; v = 0.f; }
            v = v + (xv[j][1] - v) / tb; if (v >= 1.f) { wb[1] |= m; v = 0.f; }
            v = v + (xv[j][2] - v) / tb; if (v >= 1.f) { wb[2] |= m; v = 0.f; }
            v = v + (xv[j][3] - v) / tb; if (v >= 1.f) { wb[3] |= m; }
        }
    }
    *(u32x4*)(s1p + ((size_t)s0  * 8 + wq) * 1024 + hw * 4) = (u32x4){wa[0], wa[1], wa[2], wa[3]};
    *(u32x4*)(s1p + ((size_t)s1v * 8 + wq) * 1024 + hw * 4) = (u32x4){wb[0], wb[1], wb[2], wb[3]};
}

// stage one 32KB w1 (ks) tile: hi 16KB + lo 16KB, 512 thr x 4 gl16
static __device__ __forceinline__ void stage_g1(const char* wt, char* dst, int wid, int lane) {
    #pragma unroll
    for (int i = 0; i < 4; ++i)
        gl16(wt + i * 8192 + (wid * 64 + lane) * 16, dst + i * 8192 + wid * 1024);
}

// ================= GEMM1: spikes x w1(hi/lo) + BN1 + LIF2 -> s2p =================
// block tile M=256 x N=256, 8 phases K=32 (hi+lo each). 512 thr = 8 waves (2m x 4n),
// wave-tile 128x64 (mf=8, nf=4). A per-lane from global; single barrier/phase, vmcnt(8).
__global__ __launch_bounds__(512, 2) void k_g1(const uint32_t* __restrict__ s1p,
                                               const short* __restrict__ w1c,
                                               const float* __restrict__ sc1, const float* __restrict__ sh1,
                                               const int* __restrict__ slotE,
                                               uint32_t* __restrict__ s2p) {
    __shared__ __align__(16) char SM[65536];   // 2 x 32KB B-buffers; epilogue aliases

    const int tid = threadIdx.x;
    const int wg = ((blockIdx.x & 7) << 6) | (blockIdx.x >> 3);   // XCD swizzle (512 % 8 == 0)
    const int slot = wg & 31, mt = (wg >> 5) & 3, nt = (wg >> 7) & 3;
    const int e = slotE[slot];
    const int lane = tid & 63, wid = tid >> 6;
    const int wm = wid & 1, wn = wid >> 1;
    const int l15 = lane & 15, lhi = lane >> 4;

    f32x4 acc[8][4];
    #pragma unroll
    for (int i = 0; i < 8; ++i)
        #pragma unroll
        for (int j = 0; j < 4; ++j) acc[i][j] = (f32x4){0.f, 0.f, 0.f, 0.f};

    const char* wbase = (const char*)(w1c + (size_t)((e * 4 + nt) * 8) * 16384);   // 32KB per ks
    const uint32_t* abase = s1p + (size_t)(slot * 8) * 1024 + (mt * 256 + wm * 128 + l15);

    uint32_t awA[8], awB[8];
    // prologue issue order: A(0) 8, S(0) 4, A(1) 8
    #pragma unroll
    for (int mf = 0; mf < 8; ++mf) awA[mf] = abase[mf * 16];
    SCHED0();
    stage_g1(wbase, SM, wid, lane);
    SCHED0();
    #pragma unroll
    for (int mf = 0; mf < 8; ++mf) awB[mf] = abase[1024 + mf * 16];
    SCHED0();

    #pragma unroll
    for (int p = 0; p < 8; ++p) {
        if (p < 7) asm volatile("s_waitcnt vmcnt(8)" ::: "memory");
        else       asm volatile("s_waitcnt vmcnt(0)" ::: "memory");
        SBAR();
        const short* Bb = (const short*)(SM + (p & 1) * 32768);
        short8v bh[4], bl[4];
        #pragma unroll
        for (int nf = 0; nf < 4; ++nf) {
            int n = wn * 64 + nf * 16 + l15;
            int u = (lhi ^ (n & 3) ^ ((n >> 2) & 3)) & 3;
            bh[nf] = *(const short8v*)&Bb[n * 32 + u * 8];
            bl[nf] = *(const short8v*)&Bb[8192 + n * 32 + u * 8];
        }
        uint32_t awc[8];
        #pragma unroll
        for (int mf = 0; mf < 8; ++mf) awc[mf] = (p & 1) ? awB[mf] : awA[mf];
        SCHED0();
        if (p < 7) stage_g1(wbase + (p + 1) * 32768, SM + ((p + 1) & 1) * 32768, wid, lane);
        SCHED0();
        if (p < 6) {
            #pragma unroll
            for (int mf = 0; mf < 8; ++mf) {
                uint32_t v = abase[(p + 2) * 1024 + mf * 16];
                if (p & 1) awB[mf] = v; else awA[mf] = v;
            }
        }
        SCHED0();
        __builtin_amdgcn_s_setprio(1);
        #pragma unroll
        for (int mf = 0; mf < 8; ++mf) {
            short8v af = unpack8((awc[mf] >> (lhi * 8)) & 0xffu);
            #pragma unroll
            for (int nf = 0; nf < 4; ++nf)
                acc[mf][nf] = __builtin_amdgcn_mfma_f32_16x16x32_bf16(af, bh[nf], acc[mf][nf], 0, 0, 0);
            #pragma unroll
            for (int nf = 0; nf < 4; ++nf)
                acc[mf][nf] = __builtin_amdgcn_mfma_f32_16x16x32_bf16(af, bl[nf], acc[mf][nf], 0, 0, 0);
        }
        __builtin_amdgcn_s_setprio(0);
    }

    __syncthreads();
    // epilogue: BN1 + LIF2 (4 t in each lane's acc regs) + ballot-pack
    unsigned short (*SPK)[16] = (unsigned short(*)[16])SM;
    const float tau = 1.5f + e * (2.5f / 7.0f);
    #pragma unroll
    for (int mf = 0; mf < 8; ++mf) {
        #pragma unroll
        for (int nf = 0; nf < 4; ++nf) {
            int o = nt * 256 + wn * 64 + nf * 16 + l15;
            float sc = sc1[e * 1024 + o], sh = sh1[e * 1024 + o];
            float v = 0.f;
            #pragma unroll
            for (int t = 0; t < 4; ++t) {
                float bnv = sc * acc[mf][nf][t] + sh;
                v = v + (bnv - v) / tau;
                bool sp = (v >= 1.f);
                unsigned long long bal = __ballot(sp);
                if (sp) v = 0.f;
                if (l15 == 0)
                    SPK[wm * 128 + mf * 16 + lhi * 4 + t][wn * 4 + nf] =
                        (unsigned short)((bal >> (lhi * 16)) & 0xFFFFull);
            }
        }
    }
    __syncthreads();
    if (tid < 256) {
        int row = tid;
        #pragma unroll
        for (int w = 0; w < 8; ++w) {
            uint32_t word = (uint32_t)SPK[row][2 * w] | ((uint32_t)SPK[row][2 * w + 1] << 16);
            s2p[(size_t)(slot * 32 + nt * 8 + w) * 1024 + mt * 256 + row] = word;
        }
    }
}

// stage 16KB: rank0 tile 8KB + rank1 tile 8KB, 256 thr x 4 gl16
static __device__ __forceinline__ void stage_g2(const char* w0, const char* w1, char* dst, int wid, int lane) {
    gl16(w0 + (wid * 64 + lane) * 16, dst + wid * 1024);
    gl16(w0 + 4096 + (wid * 64 + lane) * 16, dst + 4096 + wid * 1024);
    gl16(w1 + (wid * 64 + lane) * 16, dst + 8192 + wid * 1024);
    gl16(w1 + 4096 + (wid * 64 + lane) * 16, dst + 12288 + wid * 1024);
}

// ================= GEMM2: spikes2 x w2, both ranks fused, + BN2 + combine =================
// block tile M=256 x N=64, 16 phases K=64. 256 thr = 4 waves (2 rank x 2 m),
// wave-tile 128x64 (mf=8, nf=4). A per-lane from global; single barrier/phase, vmcnt(16).
__global__ __launch_bounds__(256, 2) void k_g2(const uint32_t* __restrict__ s2p,
                                               const short* __restrict__ w2t,
                                               const float* __restrict__ sc2, const float* __restrict__ sh2,
                                               const int* __restrict__ slotE, const float* __restrict__ slotW,
                                               const int* __restrict__ bslot,
                                               const float* __restrict__ x, float* __restrict__ out) {
    __shared__ __align__(16) char SM[33280];   // 2 x 16KB buffers; Y(33280) aliases

    const int tid = threadIdx.x;
    const int wg = ((blockIdx.x & 7) << 5) | (blockIdx.x >> 3);   // XCD swizzle (256 % 8 == 0)
    const int b = wg & 15, mt = (wg >> 4) & 3, nt = (wg >> 6) & 3;
    const int lane = tid & 63, wid = tid >> 6;
    const int rank = wid >> 1, wm = wid & 1;
    const int l15 = lane & 15, lhi = lane >> 4;

    const int slot = bslot[b * 2 + rank];
    const int e = slotE[slot];
    const float wgt = slotW[slot];
    const int e0 = slotE[bslot[b * 2]], e1 = slotE[bslot[b * 2 + 1]];

    f32x4 acc[8][4];
    #pragma unroll
    for (int i = 0; i < 8; ++i)
        #pragma unroll
        for (int j = 0; j < 4; ++j) acc[i][j] = (f32x4){0.f, 0.f, 0.f, 0.f};

    const char* wb0 = (const char*)(w2t + (size_t)((e0 * 4 + nt) * 16) * 4096);  // 8KB per ks
    const char* wb1 = (const char*)(w2t + (size_t)((e1 * 4 + nt) * 16) * 4096);
    const uint32_t* abase = s2p + (size_t)slot * 32768 + (mt * 256 + wm * 128 + l15);

    uint32_t awA[16], awB[16];
    // prologue issue order: A(0) 16, S(0) 4, A(1) 16
    #pragma unroll
    for (int mf = 0; mf < 8; ++mf) {
        awA[mf * 2]     = abase[mf * 16];
        awA[mf * 2 + 1] = abase[1024 + mf * 16];
    }
    SCHED0();
    stage_g2(wb0, wb1, SM, wid, lane);
    SCHED0();
    #pragma unroll
    for (int mf = 0; mf < 8; ++mf) {
        awB[mf * 2]     = abase[2048 + mf * 16];
        awB[mf * 2 + 1] = abase[3072 + mf * 16];
    }
    SCHED0();

    #pragma unroll
    for (int p = 0; p < 16; ++p) {
        if (p < 15) asm volatile("s_waitcnt vmcnt(16)" ::: "memory");
        else        asm volatile("s_waitcnt vmcnt(0)" ::: "memory");
        SBAR();
        const short* Bb = (const short*)(SM + (p & 1) * 16384 + rank * 8192);
        short8v bq[2][4];
        #pragma unroll
        for (int kf = 0; kf < 2; ++kf)
            #pragma unroll
            for (int nf = 0; nf < 4; ++nf) {
                int n = nf * 16 + l15;
                int u = (kf * 4 + lhi) ^ (n & 7);
                bq[kf][nf] = *(const short8v*)&Bb[n * 64 + u * 8];
            }
        uint32_t awc[16];
        #pragma unroll
        for (int i = 0; i < 16; ++i) awc[i] = (p & 1) ? awB[i] : awA[i];
        SCHED0();
        if (p < 15) stage_g2(wb0 + (p + 1) * 8192, wb1 + (p + 1) * 8192,
                             SM + ((p + 1) & 1) * 16384, wid, lane);
        SCHED0();
        if (p < 14) {
            #pragma unroll
            for (int mf = 0; mf < 8; ++mf) {
                uint32_t v0 = abase[(p + 2) * 2048 + mf * 16];
                uint32_t v1 = abase[(p + 2) * 2048 + 1024 + mf * 16];
                if (p & 1) { awB[mf * 2] = v0; awB[mf * 2 + 1] = v1; }
                else       { awA[mf * 2] = v0; awA[mf * 2 + 1] = v1; }
            }
        }
        SCHED0();
        __builtin_amdgcn_s_setprio(1);
        #pragma unroll
        for (int mf = 0; mf < 8; ++mf) {
            #pragma unroll
            for (int kf = 0; kf < 2; ++kf) {
                short8v af = unpack8((awc[mf * 2 + kf] >> (lhi * 8)) & 0xffu);
                #pragma unroll
                for (int nf = 0; nf < 4; ++nf)
                    acc[mf][nf] = __builtin_amdgcn_mfma_f32_16x16x32_bf16(af, bq[kf][nf], acc[mf][nf], 0, 0, 0);
            }
        }
        __builtin_amdgcn_s_setprio(0);
    }

    __syncthreads();
    // epilogue: rank1 writes wgt*y to LDS Y, rank0 adds, stream out = x + Y (two 32-hw chunks)
    float (*Y)[32][65] = (float(*)[32][65])SM;
    #pragma unroll
    for (int wmsel = 0; wmsel < 2; ++wmsel) {
        if (rank == 1 && wm == wmsel) {
            #pragma unroll
            for (int mf = 0; mf < 8; ++mf)
                #pragma unroll
                for (int nf = 0; nf < 4; ++nf) {
                    int cl = nf * 16 + l15;
                    int cg = nt * 64 + cl;
                    float sc = sc2[e * 256 + cg], sh = sh2[e * 256 + cg];
                    int hwl = mf * 4 + lhi;
                    #pragma unroll
                    for (int t = 0; t < 4; ++t)
                        Y[t][hwl][cl] = wgt * (sc * acc[mf][nf][t] + sh);
                }
        }
        __syncthreads();
        if (rank == 0 && wm == wmsel) {
            #pragma unroll
            for (int mf = 0; mf < 8; ++mf)
                #pragma unroll
                for (int nf = 0; nf < 4; ++nf) {
                    int cl = nf * 16 + l15;
                    int cg = nt * 64 + cl;
                    float sc = sc2[e * 256 + cg], sh = sh2[e * 256 + cg];
                    int hwl = mf * 4 + lhi;
                    #pragma unroll
                    for (int t = 0; t < 4; ++t)
                        Y[t][hwl][cl] += wgt * (sc * acc[mf][nf][t] + sh);
                }
        }
        __syncthreads();
        #pragma unroll
        for (int it = 0; it < 32; ++it) {
            int p2 = it * 256 + tid;
            int hwi = p2 & 31, t = (p2 >> 5) & 3, cl = p2 >> 7;
            int hwg = mt * 64 + wmsel * 32 + hwi;
            size_t oidx = ((size_t)(t * 16 + b) * 256 + nt * 64 + cl) * 256 + hwg;
            out[oidx] = x[oidx] + Y[t][hwi][cl];
        }
        __syncthreads();
    }
}

extern "C" void kernel_launch(void* const* d_in, const int* in_sizes, int n_in,
                              void* d_out, int out_size, void* d_ws, size_t ws_size,
                              hipStream_t stream) {
    const float* x   = (const float*)d_in[0];
    const float* rw  = (const float*)d_in[1];
    const float* rb  = (const float*)d_in[2];
    const float* rg  = (const float*)d_in[3];
    const float* rbt = (const float*)d_in[4];
    const float* rm  = (const float*)d_in[5];
    const float* rv  = (const float*)d_in[6];
    const float* w1  = (const float*)d_in[7];
    const float* b1  = (const float*)d_in[8];
    const float* g1  = (const float*)d_in[9];
    const float* be1 = (const float*)d_in[10];
    const float* m1  = (const float*)d_in[11];
    const float* v1  = (const float*)d_in[12];
    const float* w2  = (const float*)d_in[13];
    const float* b2  = (const float*)d_in[14];
    const float* g2  = (const float*)d_in[15];
    const float* be2 = (const float*)d_in[16];
    const float* m2  = (const float*)d_in[17];
    const float* v2  = (const float*)d_in[18];
    float* out = (float*)d_out;

    char* ws = (char*)d_ws;
    short*    w1c   = (short*)(ws);                    // 8 MiB
    short*    w2t   = (short*)(ws + 8388608);          // 4 MiB
    float*    sc1   = (float*)(ws + 12582912);         // 32 KiB
    float*    sh1   = (float*)(ws + 12615680);         // 32 KiB
    float*    sc2   = (float*)(ws + 12648448);         // 8 KiB
    float*    sh2   = (float*)(ws + 12656640);         // 8 KiB
    float*    xbar  = (float*)(ws + 12664832);         // 16 KiB
    int*      slotE = (int*)  (ws + 12681216);         // 128 B
    float*    slotW = (float*)(ws + 12681344);         // 128 B
    int*      bslot = (int*)  (ws + 12681472);         // 128 B
    uint32_t* s1p   = (uint32_t*)(ws + 12681728);      // 1 MiB
    uint32_t* s2p   = (uint32_t*)(ws + 13730304);      // 4 MiB (total ~17.1 MiB)

    k_prep<<<9248, 256, 0, stream>>>(w1, w2, x, b1, g1, be1, m1, v1, b2, g2, be2, m2, v2,
                                     w1c, w2t, sc1, sh1, sc2, sh2, xbar);
    k_r2  <<<1, 128, 0, stream>>>(xbar, rw, rb, rg, rbt, rm, rv, slotE, slotW, bslot);
    k_lif1<<<dim3(16, 8, 4), 64, 0, stream>>>(x, slotE, bslot, s1p);
    k_g1  <<<512, 512, 0, stream>>>(s1p, w1c, sc1, sh1, slotE, s2p);
    k_g2  <<<256, 256, 0, stream>>>(s2p, w2t, sc2, sh2, slotE, slotW, bslot, x, out);
}

// Round 6
// 124.049 us; speedup vs baseline: 1.2678x; 1.0086x over previous
//
#include <hip/hip_runtime.h>
#include <hip/hip_bf16.h>
#include <stdint.h>

#define EPSF 1e-5f

typedef short    short8v __attribute__((ext_vector_type(8)));
typedef float    f32x16  __attribute__((ext_vector_type(16)));
typedef uint32_t u32x4   __attribute__((ext_vector_type(4)));

// dims: T=4, B=16, C=256, H*W=256, Hid=1024, E=8, TOPK=2 -> 32 slots
// x layout (T,B,C,H,W): idx = ((t*16+b)*256+c)*256 + hw ; t-stride = 1048576

static __device__ __forceinline__ short bf16bits(float f) {
    __hip_bfloat16 h = __float2bfloat16(f);
    return *reinterpret_cast<short*>(&h);
}

// unpack 8 spike bits -> 8 bf16 (0.0 / 1.0) entirely in registers
static __device__ __forceinline__ short8v unpack8(uint32_t by) {
    uint32_t lo = ((by & 0xFu) * 0x00204081u) & 0x01010101u;
    uint32_t hi = ((by >> 4)   * 0x00204081u) & 0x01010101u;
    union { short8v s; uint32_t u[4]; } r;
    r.u[0] = __builtin_amdgcn_perm(0u, lo, 0x04010400u) * 0x3F80u;
    r.u[1] = __builtin_amdgcn_perm(0u, lo, 0x04030402u) * 0x3F80u;
    r.u[2] = __builtin_amdgcn_perm(0u, hi, 0x04010400u) * 0x3F80u;
    r.u[3] = __builtin_amdgcn_perm(0u, hi, 0x04030402u) * 0x3F80u;
    return r.s;
}

typedef const __attribute__((address_space(1))) char* gas_p;
typedef __attribute__((address_space(3))) char* las_p;
static __device__ __forceinline__ void gl16(const void* g, void* l) {
    __builtin_amdgcn_global_load_lds((gas_p)g, (las_p)l, 16, 0, 0);
}
#define SBAR()   __builtin_amdgcn_s_barrier()
#define SCHED0() __builtin_amdgcn_sched_barrier(0)

// ---------------- prep: weight convert+tile (unit-major), BN fold, router stage-1 --------
// w1c[e][nt4][ks8]{ hi:[u4][n256][8sh] , lo: +8192 sh }   8 MiB   (u = cl>>3)
// w2t[e][nt4][ks16][u8][n64][8sh]                         4 MiB   (u = kl>>3)
__global__ void k_prep(const float* __restrict__ w1, const float* __restrict__ w2,
                       const float* __restrict__ x,
                       const float* __restrict__ b1, const float* __restrict__ g1, const float* __restrict__ be1,
                       const float* __restrict__ m1, const float* __restrict__ v1,
                       const float* __restrict__ b2, const float* __restrict__ g2, const float* __restrict__ be2,
                       const float* __restrict__ m2, const float* __restrict__ v2,
                       short* __restrict__ w1c, short* __restrict__ w2t,
                       float* __restrict__ sc1, float* __restrict__ sh1,
                       float* __restrict__ sc2, float* __restrict__ sh2,
                       float* __restrict__ xbar) {
    int blk = blockIdx.x;
    if (blk < 8192) {
        int idx = blk * 256 + threadIdx.x;
        {   // w1 hi/lo split, unit-major tile
            float f = w1[idx];
            __hip_bfloat16 h = __float2bfloat16(f);
            short hb = *reinterpret_cast<short*>(&h);
            float hf = __bfloat162float(h);
            int e = idx >> 18, o = (idx >> 8) & 1023, c = idx & 255;
            int nt = o >> 8, n = o & 255, ks = c >> 5, cl = c & 31;
            int u = cl >> 3, j = cl & 7;
            size_t base = ((size_t)((e * 4 + nt) * 8 + ks)) * 16384 + u * 2048 + n * 8 + j;
            w1c[base] = hb;                      // hi plane
            w1c[base + 8192] = bf16bits(f - hf); // lo plane
        }
        {   // w2 bf16, unit-major tile
            float f = w2[idx];
            int e = idx >> 18, co = (idx >> 10) & 255, k = idx & 1023;
            int nt = co >> 6, n = co & 63, ks = k >> 6, kl = k & 63;
            int u = kl >> 3, j = kl & 7;
            size_t off = ((size_t)((e * 4 + nt) * 16 + ks)) * 4096 + u * 512 + n * 8 + j;
            w2t[off] = bf16bits(f);
        }
    } else if (blk < 8224) {
        int idx = (blk - 8192) * 256 + threadIdx.x;   // 0..8191
        {
            float s = g1[idx] / sqrtf(v1[idx] + EPSF);
            sc1[idx] = s;
            sh1[idx] = be1[idx] + s * (b1[idx] - m1[idx]);
        }
        if (idx < 2048) {
            float s = g2[idx] / sqrtf(v2[idx] + EPSF);
            sc2[idx] = s;
            sh2[idx] = be2[idx] + s * (b2[idx] - m2[idx]);
        }
    } else {
        // router stage 1: xbar[b*256+c] = mean over (T,H,W); 4 waves/block, 1 bc each
        int wid = threadIdx.x >> 6, lane = threadIdx.x & 63;
        int bc = (blk - 8224) * 4 + wid;
        const float* xp = x + (size_t)bc * 256;
        float s = 0.f;
        #pragma unroll
        for (int t = 0; t < 4; ++t)
            #pragma unroll
            for (int i = 0; i < 4; ++i)
                s += xp[(size_t)t * 1048576 + i * 64 + lane];
        #pragma unroll
        for (int off = 32; off; off >>= 1) s += __shfl_down(s, off);
        if (lane == 0) xbar[bc] = s * (1.0f / 1024.0f);
    }
}

// ---------------- router stage 2: logits -> top-2 -> expert-sorted 32 slots ----------------
__global__ void k_r2(const float* __restrict__ xbar, const float* __restrict__ rw, const float* __restrict__ rb,
                     const float* __restrict__ rg, const float* __restrict__ rbt,
                     const float* __restrict__ rm, const float* __restrict__ rv,
                     int* __restrict__ slotE, float* __restrict__ slotW, int* __restrict__ bslot) {
    __shared__ float L[16][8];
    __shared__ int   tE[32];
    __shared__ float tW[32];
    int tid = threadIdx.x; // 128
    if (tid < 128) {
        int b = tid >> 3, e = tid & 7;
        float s = 0.f;
        for (int c = 0; c < 256; ++c) s += xbar[b * 256 + c] * rw[e * 256 + c];
        s += rb[e];
        L[b][e] = rg[e] * (s - rm[e]) / sqrtf(rv[e] + EPSF) + rbt[e];
    }
    __syncthreads();
    if (tid < 16) {
        int b = tid;
        float l[8];
        #pragma unroll
        for (int e = 0; e < 8; ++e) l[e] = L[b][e];
        int i1 = 0;
        for (int e = 1; e < 8; ++e) if (l[e] > l[i1]) i1 = e;
        int i2 = (i1 == 0) ? 1 : 0;
        for (int e = 0; e < 8; ++e) { if (e == i1) continue; if (l[e] > l[i2]) i2 = e; }
        float d = l[i2] - l[i1];
        float ed = expf(d);
        tE[b * 2]     = i1; tW[b * 2]     = 1.f / (1.f + ed);
        tE[b * 2 + 1] = i2; tW[b * 2 + 1] = ed / (1.f + ed);
    }
    __syncthreads();
    if (tid == 0) {
        int pos = 0;
        for (int e = 0; e < 8; ++e)
            for (int i = 0; i < 32; ++i)
                if (tE[i] == e) {
                    slotE[pos] = e; slotW[pos] = tW[i];
                    bslot[i] = pos; ++pos;
                }
    }
}

// ---------------- LIF1: 32 routed slots, x read once, ILP-heavy ----------------
// grid (16 b, 8 wq, 4 hwq) x 64 thr. s1p[slot][ks(8)][row(1024)] u32, row = hw*4+t.
__global__ __launch_bounds__(64) void k_lif1(const float* __restrict__ x, const int* __restrict__ slotE,
                                             const int* __restrict__ bslot, uint32_t* __restrict__ s1p) {
    const int b = blockIdx.x, wq = blockIdx.y, hwq = blockIdx.z;
    const int s0 = bslot[b * 2], s1v = bslot[b * 2 + 1];
    const float ta = 1.5f + slotE[s0]  * (2.5f / 7.0f);
    const float tb = 1.5f + slotE[s1v] * (2.5f / 7.0f);
    const int lane = threadIdx.x;
    const int hw = hwq * 64 + lane;
    uint32_t wa[4] = {0, 0, 0, 0}, wb[4] = {0, 0, 0, 0};
    const float* xb = x + (size_t)b * 65536 + (size_t)wq * 8192 + hw;
    #pragma unroll
    for (int j0 = 0; j0 < 32; j0 += 8) {
        float xv[8][4];
        #pragma unroll
        for (int j = 0; j < 8; ++j)
            #pragma unroll
            for (int t = 0; t < 4; ++t)
                xv[j][t] = xb[(size_t)t * 1048576 + (size_t)(j0 + j) * 256];
        #pragma unroll
        for (int j = 0; j < 8; ++j) {
            const uint32_t m = 1u << (j0 + j);
            float v;
            v = xv[j][0] / ta;          if (v >= 1.f) { wa[0] |= m; v = 0.f; }
            v = v + (xv[j][1] - v) / ta; if (v >= 1.f) { wa[1] |= m; v = 0.f; }
            v = v + (xv[j][2] - v) / ta; if (v >= 1.f) { wa[2] |= m; v = 0.f; }
            v = v + (xv[j][3] - v) / ta; if (v >= 1.f) { wa[3] |= m; }
            v = xv[j][0] / tb;          if (v >= 1.f) { wb[0] |= m; v = 0.f; }
            v = v + (xv[j][1] - v) / tb; if (v >= 1.f) { wb[1] |= m; v = 0.f; }
            v = v + (xv[j][2] - v) / tb; if (v >= 1.f) { wb[2] |= m; v = 0.f; }
            v = v + (xv[j][3] - v) / tb; if (v >= 1.f) { wb[3] |= m; }
        }
    }
    *(u32x4*)(s1p + ((size_t)s0  * 8 + wq) * 1024 + hw * 4) = (u32x4){wa[0], wa[1], wa[2], wa[3]};
    *(u32x4*)(s1p + ((size_t)s1v * 8 + wq) * 1024 + hw * 4) = (u32x4){wb[0], wb[1], wb[2], wb[3]};
}

// stage one 32KB w1 (ks) tile: hi 16KB + lo 16KB, 512 thr x 4 gl16 (linear)
static __device__ __forceinline__ void stage_g1(const char* wt, char* dst, int wid, int lane) {
    #pragma unroll
    for (int i = 0; i < 4; ++i)
        gl16(wt + i * 8192 + (wid * 64 + lane) * 16, dst + i * 8192 + wid * 1024);
}

// ================= GEMM1: spikes x w1(hi/lo) + BN1 + LIF2 -> s2p =================
// block tile M=256 x N=256, 8 phases K=32 (hi+lo). 512 thr = 8 waves (2m x 4n),
// wave-tile 128x64 via mfma_32x32x16 (mf=4, nf=2, ks=2). Single barrier/phase, vmcnt(4).
__global__ __launch_bounds__(512, 2) void k_g1(const uint32_t* __restrict__ s1p,
                                               const short* __restrict__ w1c,
                                               const float* __restrict__ sc1, const float* __restrict__ sh1,
                                               const int* __restrict__ slotE,
                                               uint32_t* __restrict__ s2p) {
    __shared__ __align__(16) char SM[65536];   // 2 x 32KB B-buffers

    const int tid = threadIdx.x;
    const int wg = ((blockIdx.x & 7) << 6) | (blockIdx.x >> 3);   // XCD swizzle (512 % 8 == 0)
    const int slot = wg & 31, mt = (wg >> 5) & 3, nt = (wg >> 7) & 3;
    const int e = slotE[slot];
    const int lane = tid & 63, wid = tid >> 6;
    const int wm = wid & 1, wn = wid >> 1;        // wn 0..3
    const int l31 = lane & 31, hi5 = lane >> 5;

    f32x16 acc[4][2];
    #pragma unroll
    for (int i = 0; i < 4; ++i)
        #pragma unroll
        for (int j = 0; j < 2; ++j) acc[i][j] = (f32x16)(0.f);

    const char* wbase = (const char*)(w1c + (size_t)((e * 4 + nt) * 8) * 16384);   // 32KB per ks
    const uint32_t* abase = s1p + (size_t)(slot * 8) * 1024 + (mt * 256 + wm * 128 + l31);

    uint32_t awA[4], awB[4];
    // prologue issue order: A(0) 4, S(0) 4, A(1) 4
    #pragma unroll
    for (int mf = 0; mf < 4; ++mf) awA[mf] = abase[mf * 32];
    SCHED0();
    stage_g1(wbase, SM, wid, lane);
    SCHED0();
    #pragma unroll
    for (int mf = 0; mf < 4; ++mf) awB[mf] = abase[1024 + mf * 32];
    SCHED0();

    #pragma unroll
    for (int p = 0; p < 8; ++p) {
        if (p < 7) asm volatile("s_waitcnt vmcnt(4)" ::: "memory");
        else       asm volatile("s_waitcnt vmcnt(0)" ::: "memory");
        SBAR();
        const short* Bb = (const short*)(SM + (p & 1) * 32768);
        // B frags: unit-major -> 32 consecutive lanes read contiguous 16B units (no conflicts)
        short8v bh[2][2], bl[2][2];   // [ks][nf]
        #pragma unroll
        for (int ks = 0; ks < 2; ++ks)
            #pragma unroll
            for (int nf = 0; nf < 2; ++nf) {
                int n = wn * 64 + nf * 32 + l31;
                int u = ks * 2 + hi5;
                bh[ks][nf] = *(const short8v*)&Bb[u * 2048 + n * 8];
                bl[ks][nf] = *(const short8v*)&Bb[8192 + u * 2048 + n * 8];
            }
        uint32_t awc[4];
        #pragma unroll
        for (int mf = 0; mf < 4; ++mf) awc[mf] = (p & 1) ? awB[mf] : awA[mf];
        SCHED0();
        if (p < 7) stage_g1(wbase + (p + 1) * 32768, SM + ((p + 1) & 1) * 32768, wid, lane);
        SCHED0();
        if (p < 6) {
            #pragma unroll
            for (int mf = 0; mf < 4; ++mf) {
                uint32_t v = abase[(p + 2) * 1024 + mf * 32];
                if (p & 1) awB[mf] = v; else awA[mf] = v;
            }
        }
        SCHED0();
        __builtin_amdgcn_s_setprio(1);
        #pragma unroll
        for (int mf = 0; mf < 4; ++mf) {
            #pragma unroll
            for (int ks = 0; ks < 2; ++ks) {
                short8v af = unpack8((awc[mf] >> ((ks * 2 + hi5) * 8)) & 0xffu);
                #pragma unroll
                for (int nf = 0; nf < 2; ++nf) {
                    acc[mf][nf] = __builtin_amdgcn_mfma_f32_32x32x16_bf16(af, bh[ks][nf], acc[mf][nf], 0, 0, 0);
                    acc[mf][nf] = __builtin_amdgcn_mfma_f32_32x32x16_bf16(af, bl[ks][nf], acc[mf][nf], 0, 0, 0);
                }
            }
        }
        __builtin_amdgcn_s_setprio(0);
    }

    // epilogue: BN1 + LIF2 + ballot -> direct global stores (no LDS)
    // C layout 32x32: col=lane&31, row = 4*(2q+hi5) + t, q=reg>>2, t=reg&3
    const float tau = 1.5f + e * (2.5f / 7.0f);
    #pragma unroll
    for (int mf = 0; mf < 4; ++mf) {
        #pragma unroll
        for (int nf = 0; nf < 2; ++nf) {
            int o = nt * 256 + wn * 64 + nf * 32 + l31;
            float sc = sc1[e * 1024 + o], sh = sh1[e * 1024 + o];
            int w = nt * 8 + wn * 2 + nf;
            #pragma unroll
            for (int q = 0; q < 4; ++q) {
                float v = 0.f;
                #pragma unroll
                for (int t = 0; t < 4; ++t) {
                    float bnv = sc * acc[mf][nf][q * 4 + t] + sh;
                    v = v + (bnv - v) / tau;
                    bool sp = (v >= 1.f);
                    unsigned long long bal = __ballot(sp);
                    if (sp) v = 0.f;
                    if (l31 == 0) {
                        int row = mt * 256 + wm * 128 + mf * 32 + (q * 2 + hi5) * 4 + t;
                        s2p[(size_t)(slot * 32 + w) * 1024 + row] = (uint32_t)(bal >> (hi5 * 32));
                    }
                }
            }
        }
    }
}

// stage 16KB: rank0 tile 8KB + rank1 tile 8KB, 256 thr x 4 gl16 (linear)
static __device__ __forceinline__ void stage_g2(const char* w0, const char* w1, char* dst, int wid, int lane) {
    gl16(w0 + (wid * 64 + lane) * 16, dst + wid * 1024);
    gl16(w0 + 4096 + (wid * 64 + lane) * 16, dst + 4096 + wid * 1024);
    gl16(w1 + (wid * 64 + lane) * 16, dst + 8192 + wid * 1024);
    gl16(w1 + 4096 + (wid * 64 + lane) * 16, dst + 12288 + wid * 1024);
}

// ================= GEMM2: spikes2 x w2, both ranks fused, + BN2 + combine =================
// block tile M=256 x N=64, 16 phases K=64. 256 thr = 4 waves (2 rank x 2 m),
// wave-tile 128x64 via mfma_32x32x16 (mf=4, nf=2, ks=4). Single barrier/phase, vmcnt(8).
__global__ __launch_bounds__(256, 2) void k_g2(const uint32_t* __restrict__ s2p,
                                               const short* __restrict__ w2t,
                                               const float* __restrict__ sc2, const float* __restrict__ sh2,
                                               const int* __restrict__ slotE, const float* __restrict__ slotW,
                                               const int* __restrict__ bslot,
                                               const float* __restrict__ x, float* __restrict__ out) {
    __shared__ __align__(16) char SM[33280];   // 2 x 16KB buffers; Y aliases

    const int tid = threadIdx.x;
    const int wg = ((blockIdx.x & 7) << 5) | (blockIdx.x >> 3);   // XCD swizzle (256 % 8 == 0)
    const int b = wg & 15, mt = (wg >> 4) & 3, nt = (wg >> 6) & 3;
    const int lane = tid & 63, wid = tid >> 6;
    const int rank = wid >> 1, wm = wid & 1;
    const int l31 = lane & 31, hi5 = lane >> 5;

    const int slot = bslot[b * 2 + rank];
    const int e = slotE[slot];
    const float wgt = slotW[slot];
    const int e0 = slotE[bslot[b * 2]], e1 = slotE[bslot[b * 2 + 1]];

    f32x16 acc[4][2];
    #pragma unroll
    for (int i = 0; i < 4; ++i)
        #pragma unroll
        for (int j = 0; j < 2; ++j) acc[i][j] = (f32x16)(0.f);

    const char* wb0 = (const char*)(w2t + (size_t)((e0 * 4 + nt) * 16) * 4096);  // 8KB per ks
    const char* wb1 = (const char*)(w2t + (size_t)((e1 * 4 + nt) * 16) * 4096);
    const uint32_t* abase = s2p + (size_t)slot * 32768 + (mt * 256 + wm * 128 + l31);

    uint32_t awA[4][2], awB[4][2];
    // prologue issue order: A(0) 8, S(0) 4, A(1) 8
    #pragma unroll
    for (int mf = 0; mf < 4; ++mf) {
        awA[mf][0] = abase[mf * 32];
        awA[mf][1] = abase[1024 + mf * 32];
    }
    SCHED0();
    stage_g2(wb0, wb1, SM, wid, lane);
    SCHED0();
    #pragma unroll
    for (int mf = 0; mf < 4; ++mf) {
        awB[mf][0] = abase[2048 + mf * 32];
        awB[mf][1] = abase[3072 + mf * 32];
    }
    SCHED0();

    #pragma unroll
    for (int p = 0; p < 16; ++p) {
        if (p < 15) asm volatile("s_waitcnt vmcnt(8)" ::: "memory");
        else        asm volatile("s_waitcnt vmcnt(0)" ::: "memory");
        SBAR();
        const short* Bb = (const short*)(SM + (p & 1) * 16384 + rank * 8192);
        short8v bq[4][2];   // [ks][nf], unit-major reads: conflict-free
        #pragma unroll
        for (int ks = 0; ks < 4; ++ks)
            #pragma unroll
            for (int nf = 0; nf < 2; ++nf) {
                int n = nf * 32 + l31;
                int u = ks * 2 + hi5;
                bq[ks][nf] = *(const short8v*)&Bb[u * 512 + n * 8];
            }
        uint32_t awc[4][2];
        #pragma unroll
        for (int mf = 0; mf < 4; ++mf) {
            awc[mf][0] = (p & 1) ? awB[mf][0] : awA[mf][0];
            awc[mf][1] = (p & 1) ? awB[mf][1] : awA[mf][1];
        }
        SCHED0();
        if (p < 15) stage_g2(wb0 + (p + 1) * 8192, wb1 + (p + 1) * 8192,
                             SM + ((p + 1) & 1) * 16384, wid, lane);
        SCHED0();
        if (p < 14) {
            #pragma unroll
            for (int mf = 0; mf < 4; ++mf) {
                uint32_t v0 = abase[(p + 2) * 2048 + mf * 32];
                uint32_t v1 = abase[(p + 2) * 2048 + 1024 + mf * 32];
                if (p & 1) { awB[mf][0] = v0; awB[mf][1] = v1; }
                else       { awA[mf][0] = v0; awA[mf][1] = v1; }
            }
        }
        SCHED0();
        __builtin_amdgcn_s_setprio(1);
        #pragma unroll
        for (int mf = 0; mf < 4; ++mf) {
            #pragma unroll
            for (int ks = 0; ks < 4; ++ks) {
                short8v af = unpack8((awc[mf][ks >> 1] >> (((ks & 1) * 2 + hi5) * 8)) & 0xffu);
                #pragma unroll
                for (int nf = 0; nf < 2; ++nf)
                    acc[mf][nf] = __builtin_amdgcn_mfma_f32_32x32x16_bf16(af, bq[ks][nf], acc[mf][nf], 0, 0, 0);
            }
        }
        __builtin_amdgcn_s_setprio(0);
    }

    __syncthreads();
    // epilogue: rank1 writes wgt*y to LDS Y, rank0 adds, stream out = x + Y (two 32-hw chunks)
    float (*Y)[32][65] = (float(*)[32][65])SM;
    #pragma unroll
    for (int ch = 0; ch < 2; ++ch) {
        if (rank == 1 && wm == ch) {
            #pragma unroll
            for (int mf = 0; mf < 4; ++mf)
                #pragma unroll
                for (int nf = 0; nf < 2; ++nf) {
                    int cl = nf * 32 + l31;
                    int cg = nt * 64 + cl;
                    float sc = sc2[e * 256 + cg], sh = sh2[e * 256 + cg];
                    #pragma unroll
                    for (int q = 0; q < 4; ++q) {
                        int hwl = mf * 8 + q * 2 + hi5;
                        #pragma unroll
                        for (int t = 0; t < 4; ++t)
                            Y[t][hwl][cl] = wgt * (sc * acc[mf][nf][q * 4 + t] + sh);
                    }
                }
        }
        __syncthreads();
        if (rank == 0 && wm == ch) {
            #pragma unroll
            for (int mf = 0; mf < 4; ++mf)
                #pragma unroll
                for (int nf = 0; nf < 2; ++nf) {
                    int cl = nf * 32 + l31;
                    int cg = nt * 64 + cl;
                    float sc = sc2[e * 256 + cg], sh = sh2[e * 256 + cg];
                    #pragma unroll
                    for (int q = 0; q < 4; ++q) {
                        int hwl = mf * 8 + q * 2 + hi5;
                        #pragma unroll
                        for (int t = 0; t < 4; ++t)
                            Y[t][hwl][cl] += wgt * (sc * acc[mf][nf][q * 4 + t] + sh);
                    }
                }
        }
        __syncthreads();
        #pragma unroll
        for (int it = 0; it < 32; ++it) {
            int p2 = it * 256 + tid;
            int hwi = p2 & 31, t = (p2 >> 5) & 3, cl = p2 >> 7;
            size_t oidx = ((size_t)(t * 16 + b) * 256 + nt * 64 + cl) * 256 + (mt * 64 + ch * 32 + hwi);
            out[oidx] = x[oidx] + Y[t][hwi][cl];
        }
        __syncthreads();
    }
}

extern "C" void kernel_launch(void* const* d_in, const int* in_sizes, int n_in,
                              void* d_out, int out_size, void* d_ws, size_t ws_size,
                              hipStream_t stream) {
    const float* x   = (const float*)d_in[0];
    const float* rw  = (const float*)d_in[1];
    const float* rb  = (const float*)d_in[2];
    const float* rg  = (const float*)d_in[3];
    const float* rbt = (const float*)d_in[4];
    const float* rm  = (const float*)d_in[5];
    const float* rv  = (const float*)d_in[6];
    const float* w1  = (const float*)d_in[7];
    const float* b1  = (const float*)d_in[8];
    const float* g1  = (const float*)d_in[9];
    const float* be1 = (const float*)d_in[10];
    const float* m1  = (const float*)d_in[11];
    const float* v1  = (const float*)d_in[12];
    const float* w2  = (const float*)d_in[13];
    const float* b2  = (const float*)d_in[14];
    const float* g2  = (const float*)d_in[15];
    const float* be2 = (const float*)d_in[16];
    const float* m2  = (const float*)d_in[17];
    const float* v2  = (const float*)d_in[18];
    float* out = (float*)d_out;

    char* ws = (char*)d_ws;
    short*    w1c   = (short*)(ws);                    // 8 MiB
    short*    w2t   = (short*)(ws + 8388608);          // 4 MiB
    float*    sc1   = (float*)(ws + 12582912);         // 32 KiB
    float*    sh1   = (float*)(ws + 12615680);         // 32 KiB
    float*    sc2   = (float*)(ws + 12648448);         // 8 KiB
    float*    sh2   = (float*)(ws + 12656640);         // 8 KiB
    float*    xbar  = (float*)(ws + 12664832);         // 16 KiB
    int*      slotE = (int*)  (ws + 12681216);         // 128 B
    float*    slotW = (float*)(ws + 12681344);         // 128 B
    int*      bslot = (int*)  (ws + 12681472);         // 128 B
    uint32_t* s1p   = (uint32_t*)(ws + 12681728);      // 1 MiB
    uint32_t* s2p   = (uint32_t*)(ws + 13730304);      // 4 MiB (total ~17.1 MiB)

    k_prep<<<9248, 256, 0, stream>>>(w1, w2, x, b1, g1, be1, m1, v1, b2, g2, be2, m2, v2,
                                     w1c, w2t, sc1, sh1, sc2, sh2, xbar);
    k_r2  <<<1, 128, 0, stream>>>(xbar, rw, rb, rg, rbt, rm, rv, slotE, slotW, bslot);
    k_lif1<<<dim3(16, 8, 4), 64, 0, stream>>>(x, slotE, bslot, s1p);
    k_g1  <<<512, 512, 0, stream>>>(s1p, w1c, sc1, sh1, slotE, s2p);
    k_g2  <<<256, 256, 0, stream>>>(s2p, w2t, sc2, sh2, slotE, slotW, bslot, x, out);
}

// Round 7
// 112.324 us; speedup vs baseline: 1.4001x; 1.1044x over previous
//
#include <hip/hip_runtime.h>
#include <hip/hip_bf16.h>
#include <stdint.h>

#define EPSF 1e-5f

typedef short    short8v __attribute__((ext_vector_type(8)));
typedef float    f32x16  __attribute__((ext_vector_type(16)));
typedef uint32_t u32x4   __attribute__((ext_vector_type(4)));

// dims: T=4, B=16, C=256, H*W=256, Hid=1024, E=8, TOPK=2 -> 32 slots
// x layout (T,B,C,H,W): idx = ((t*16+b)*256+c)*256 + hw ; t-stride = 1048576

static __device__ __forceinline__ short bf16bits(float f) {
    __hip_bfloat16 h = __float2bfloat16(f);
    return *reinterpret_cast<short*>(&h);
}

// unpack 8 spike bits -> 8 bf16 (0.0 / 1.0) entirely in registers
static __device__ __forceinline__ short8v unpack8(uint32_t by) {
    uint32_t lo = ((by & 0xFu) * 0x00204081u) & 0x01010101u;
    uint32_t hi = ((by >> 4)   * 0x00204081u) & 0x01010101u;
    union { short8v s; uint32_t u[4]; } r;
    r.u[0] = __builtin_amdgcn_perm(0u, lo, 0x04010400u) * 0x3F80u;
    r.u[1] = __builtin_amdgcn_perm(0u, lo, 0x04030402u) * 0x3F80u;
    r.u[2] = __builtin_amdgcn_perm(0u, hi, 0x04010400u) * 0x3F80u;
    r.u[3] = __builtin_amdgcn_perm(0u, hi, 0x04030402u) * 0x3F80u;
    return r.s;
}

#define SCHED0() __builtin_amdgcn_sched_barrier(0)

// ---------------- prep: weight convert+tile (unit-major), BN fold, router stage-1 --------
// w1c[e][nt4][ks8]{ hi:[u4][n256][8sh] , lo: +8192 sh }   8 MiB   (u = cl>>3)
// w2t[e][ntw4][ks16][u8][n64][8sh]                        4 MiB   (u = kl>>3)
__global__ void k_prep(const float* __restrict__ w1, const float* __restrict__ w2,
                       const float* __restrict__ x,
                       const float* __restrict__ b1, const float* __restrict__ g1, const float* __restrict__ be1,
                       const float* __restrict__ m1, const float* __restrict__ v1,
                       const float* __restrict__ b2, const float* __restrict__ g2, const float* __restrict__ be2,
                       const float* __restrict__ m2, const float* __restrict__ v2,
                       short* __restrict__ w1c, short* __restrict__ w2t,
                       float* __restrict__ sc1, float* __restrict__ sh1,
                       float* __restrict__ sc2, float* __restrict__ sh2,
                       float* __restrict__ xbar) {
    int blk = blockIdx.x;
    if (blk < 8192) {
        int idx = blk * 256 + threadIdx.x;
        {   // w1 hi/lo split, unit-major tile
            float f = w1[idx];
            __hip_bfloat16 h = __float2bfloat16(f);
            short hb = *reinterpret_cast<short*>(&h);
            float hf = __bfloat162float(h);
            int e = idx >> 18, o = (idx >> 8) & 1023, c = idx & 255;
            int nt = o >> 8, n = o & 255, ks = c >> 5, cl = c & 31;
            int u = cl >> 3, j = cl & 7;
            size_t base = ((size_t)((e * 4 + nt) * 8 + ks)) * 16384 + u * 2048 + n * 8 + j;
            w1c[base] = hb;                      // hi plane
            w1c[base + 8192] = bf16bits(f - hf); // lo plane
        }
        {   // w2 bf16, unit-major tile
            float f = w2[idx];
            int e = idx >> 18, co = (idx >> 10) & 255, k = idx & 1023;
            int nt = co >> 6, n = co & 63, ks = k >> 6, kl = k & 63;
            int u = kl >> 3, j = kl & 7;
            size_t off = ((size_t)((e * 4 + nt) * 16 + ks)) * 4096 + u * 512 + n * 8 + j;
            w2t[off] = bf16bits(f);
        }
    } else if (blk < 8224) {
        int idx = (blk - 8192) * 256 + threadIdx.x;   // 0..8191
        {
            float s = g1[idx] / sqrtf(v1[idx] + EPSF);
            sc1[idx] = s;
            sh1[idx] = be1[idx] + s * (b1[idx] - m1[idx]);
        }
        if (idx < 2048) {
            float s = g2[idx] / sqrtf(v2[idx] + EPSF);
            sc2[idx] = s;
            sh2[idx] = be2[idx] + s * (b2[idx] - m2[idx]);
        }
    } else {
        // router stage 1: xbar[b*256+c] = mean over (T,H,W); 4 waves/block, 1 bc each
        int wid = threadIdx.x >> 6, lane = threadIdx.x & 63;
        int bc = (blk - 8224) * 4 + wid;
        const float* xp = x + (size_t)bc * 256;
        float s = 0.f;
        #pragma unroll
        for (int t = 0; t < 4; ++t)
            #pragma unroll
            for (int i = 0; i < 4; ++i)
                s += xp[(size_t)t * 1048576 + i * 64 + lane];
        #pragma unroll
        for (int off = 32; off; off >>= 1) s += __shfl_down(s, off);
        if (lane == 0) xbar[bc] = s * (1.0f / 1024.0f);
    }
}

// ---------------- router stage 2: logits -> top-2 -> expert-sorted 32 slots ----------------
__global__ void k_r2(const float* __restrict__ xbar, const float* __restrict__ rw, const float* __restrict__ rb,
                     const float* __restrict__ rg, const float* __restrict__ rbt,
                     const float* __restrict__ rm, const float* __restrict__ rv,
                     int* __restrict__ slotE, float* __restrict__ slotW, int* __restrict__ bslot) {
    __shared__ float L[16][8];
    __shared__ int   tE[32];
    __shared__ float tW[32];
    int tid = threadIdx.x; // 128
    if (tid < 128) {
        int b = tid >> 3, e = tid & 7;
        float s = 0.f;
        for (int c = 0; c < 256; ++c) s += xbar[b * 256 + c] * rw[e * 256 + c];
        s += rb[e];
        L[b][e] = rg[e] * (s - rm[e]) / sqrtf(rv[e] + EPSF) + rbt[e];
    }
    __syncthreads();
    if (tid < 16) {
        int b = tid;
        float l[8];
        #pragma unroll
        for (int e = 0; e < 8; ++e) l[e] = L[b][e];
        int i1 = 0;
        for (int e = 1; e < 8; ++e) if (l[e] > l[i1]) i1 = e;
        int i2 = (i1 == 0) ? 1 : 0;
        for (int e = 0; e < 8; ++e) { if (e == i1) continue; if (l[e] > l[i2]) i2 = e; }
        float d = l[i2] - l[i1];
        float ed = expf(d);
        tE[b * 2]     = i1; tW[b * 2]     = 1.f / (1.f + ed);
        tE[b * 2 + 1] = i2; tW[b * 2 + 1] = ed / (1.f + ed);
    }
    __syncthreads();
    if (tid == 0) {
        int pos = 0;
        for (int e = 0; e < 8; ++e)
            for (int i = 0; i < 32; ++i)
                if (tE[i] == e) {
                    slotE[pos] = e; slotW[pos] = tW[i];
                    bslot[i] = pos; ++pos;
                }
    }
}

// ---------------- LIF1: 32 routed slots, x read once, ILP-heavy ----------------
// grid (16 b, 8 wq, 4 hwq) x 64 thr. s1p[slot][ks(8)][row(1024)] u32, row = hw*4+t.
__global__ __launch_bounds__(64) void k_lif1(const float* __restrict__ x, const int* __restrict__ slotE,
                                             const int* __restrict__ bslot, uint32_t* __restrict__ s1p) {
    const int b = blockIdx.x, wq = blockIdx.y, hwq = blockIdx.z;
    const int s0 = bslot[b * 2], s1v = bslot[b * 2 + 1];
    const float ta = 1.5f + slotE[s0]  * (2.5f / 7.0f);
    const float tb = 1.5f + slotE[s1v] * (2.5f / 7.0f);
    const int lane = threadIdx.x;
    const int hw = hwq * 64 + lane;
    uint32_t wa[4] = {0, 0, 0, 0}, wb[4] = {0, 0, 0, 0};
    const float* xb = x + (size_t)b * 65536 + (size_t)wq * 8192 + hw;
    #pragma unroll
    for (int j0 = 0; j0 < 32; j0 += 8) {
        float xv[8][4];
        #pragma unroll
        for (int j = 0; j < 8; ++j)
            #pragma unroll
            for (int t = 0; t < 4; ++t)
                xv[j][t] = xb[(size_t)t * 1048576 + (size_t)(j0 + j) * 256];
        #pragma unroll
        for (int j = 0; j < 8; ++j) {
            const uint32_t m = 1u << (j0 + j);
            float v;
            v = xv[j][0] / ta;          if (v >= 1.f) { wa[0] |= m; v = 0.f; }
            v = v + (xv[j][1] - v) / ta; if (v >= 1.f) { wa[1] |= m; v = 0.f; }
            v = v + (xv[j][2] - v) / ta; if (v >= 1.f) { wa[2] |= m; v = 0.f; }
            v = v + (xv[j][3] - v) / ta; if (v >= 1.f) { wa[3] |= m; }
            v = xv[j][0] / tb;          if (v >= 1.f) { wb[0] |= m; v = 0.f; }
            v = v + (xv[j][1] - v) / tb; if (v >= 1.f) { wb[1] |= m; v = 0.f; }
            v = v + (xv[j][2] - v) / tb; if (v >= 1.f) { wb[2] |= m; v = 0.f; }
            v = v + (xv[j][3] - v) / tb; if (v >= 1.f) { wb[3] |= m; }
        }
    }
    *(u32x4*)(s1p + ((size_t)s0  * 8 + wq) * 1024 + hw * 4) = (u32x4){wa[0], wa[1], wa[2], wa[3]};
    *(u32x4*)(s1p + ((size_t)s1v * 8 + wq) * 1024 + hw * 4) = (u32x4){wb[0], wb[1], wb[2], wb[3]};
}

// ================= GEMM1: register-direct, barrier-free. spikes x w1(hi/lo) + BN1 + LIF2 -> s2p ====
// grid 1024 = slot(32) x mrow(8) x nt(4); 256 thr = 4 waves, wave-tile 128 x 64.
// 8 phases of K=32 (hi+lo), B direct from L2 (per-XCD slice ~2MB), reg double-buffer.
__global__ __launch_bounds__(256, 2) void k_g1(const uint32_t* __restrict__ s1p,
                                               const short* __restrict__ w1c,
                                               const float* __restrict__ sc1, const float* __restrict__ sh1,
                                               const int* __restrict__ slotE,
                                               uint32_t* __restrict__ s2p) {
    const int tid = threadIdx.x, bid = blockIdx.x;
    const int wg = ((bid & 7) << 7) | (bid >> 3);      // XCD swizzle: nt uniform per XCD-pair
    const int slot = wg & 31, mrow = (wg >> 5) & 7, nt = wg >> 8;
    const int e = slotE[slot];
    const int lane = tid & 63, wid = tid >> 6;
    const int l31 = lane & 31, hi5 = lane >> 5;

    f32x16 acc[4][2];
    #pragma unroll
    for (int i = 0; i < 4; ++i)
        #pragma unroll
        for (int j = 0; j < 2; ++j) acc[i][j] = (f32x16)(0.f);

    const short* wbase = w1c + (size_t)((e * 4 + nt) * 8) * 16384 + hi5 * 2048 + (wid * 64 + l31) * 8;
    const uint32_t* abase = s1p + (size_t)slot * 8192 + mrow * 128 + l31;

    short8v b0[8], b1[8];
    uint32_t a0[4], a1[4];

#define G1_LDB(P, B) { const short* wp = wbase + (size_t)(P) * 16384; \
    B[0] = *(const short8v*)(wp);                B[1] = *(const short8v*)(wp + 256); \
    B[2] = *(const short8v*)(wp + 4096);         B[3] = *(const short8v*)(wp + 4352); \
    B[4] = *(const short8v*)(wp + 8192);         B[5] = *(const short8v*)(wp + 8448); \
    B[6] = *(const short8v*)(wp + 12288);        B[7] = *(const short8v*)(wp + 12544); }
#define G1_LDA(P, A) { _Pragma("unroll") for (int mf = 0; mf < 4; ++mf) A[mf] = abase[(P) * 1024 + mf * 32]; }
#define G1_MM(A, B) { \
    __builtin_amdgcn_s_setprio(1); \
    _Pragma("unroll") for (int mf = 0; mf < 4; ++mf) \
      _Pragma("unroll") for (int ks = 0; ks < 2; ++ks) { \
        short8v af = unpack8((A[mf] >> ((ks * 2 + hi5) * 8)) & 0xffu); \
        _Pragma("unroll") for (int nf = 0; nf < 2; ++nf) { \
          acc[mf][nf] = __builtin_amdgcn_mfma_f32_32x32x16_bf16(af, B[ks * 2 + nf], acc[mf][nf], 0, 0, 0); \
          acc[mf][nf] = __builtin_amdgcn_mfma_f32_32x32x16_bf16(af, B[4 + ks * 2 + nf], acc[mf][nf], 0, 0, 0); \
        } } \
    __builtin_amdgcn_s_setprio(0); }

    G1_LDA(0, a0); G1_LDB(0, b0);
    G1_LDA(1, a1); G1_LDB(1, b1);
    G1_MM(a0, b0); SCHED0();
    G1_LDA(2, a0); G1_LDB(2, b0); G1_MM(a1, b1); SCHED0();
    G1_LDA(3, a1); G1_LDB(3, b1); G1_MM(a0, b0); SCHED0();
    G1_LDA(4, a0); G1_LDB(4, b0); G1_MM(a1, b1); SCHED0();
    G1_LDA(5, a1); G1_LDB(5, b1); G1_MM(a0, b0); SCHED0();
    G1_LDA(6, a0); G1_LDB(6, b0); G1_MM(a1, b1); SCHED0();
    G1_LDA(7, a1); G1_LDB(7, b1); G1_MM(a0, b0); SCHED0();
    G1_MM(a1, b1);

    // epilogue: BN1 + LIF2 + ballot -> direct global stores (no LDS)
    // C layout 32x32: col=l31, row = 8q + 4*hi5 + t  (reg = q*4 + t)
    const float tau = 1.5f + e * (2.5f / 7.0f);
    #pragma unroll
    for (int mf = 0; mf < 4; ++mf) {
        #pragma unroll
        for (int nf = 0; nf < 2; ++nf) {
            int o = nt * 256 + wid * 64 + nf * 32 + l31;
            float sc = sc1[e * 1024 + o], sh = sh1[e * 1024 + o];
            int w = nt * 8 + wid * 2 + nf;
            #pragma unroll
            for (int q = 0; q < 4; ++q) {
                float v = 0.f;
                #pragma unroll
                for (int t = 0; t < 4; ++t) {
                    float bnv = sc * acc[mf][nf][q * 4 + t] + sh;
                    v = v + (bnv - v) / tau;
                    bool sp = (v >= 1.f);
                    unsigned long long bal = __ballot(sp);
                    if (sp) v = 0.f;
                    if (l31 == 0) {
                        int row = mrow * 128 + mf * 32 + q * 8 + hi5 * 4 + t;
                        s2p[(size_t)(slot * 32 + w) * 1024 + row] = (uint32_t)(bal >> (hi5 * 32));
                    }
                }
            }
        }
    }
#undef G1_LDB
#undef G1_LDA
#undef G1_MM
}

// ================= GEMM2: register-direct, both ranks fused, + BN2 + combine =================
// grid 512 = b(16) x mt(4) x nt(8 of 32 cols); 256 thr = 4 waves (rank2 x wm2), wave-tile 128 x 32.
// 16 phases of K=64. LDS used ONLY for the rank-combine Y epilogue.
__global__ __launch_bounds__(256, 2) void k_g2(const uint32_t* __restrict__ s2p,
                                               const short* __restrict__ w2t,
                                               const float* __restrict__ sc2, const float* __restrict__ sh2,
                                               const int* __restrict__ slotE, const float* __restrict__ slotW,
                                               const int* __restrict__ bslot,
                                               const float* __restrict__ x, float* __restrict__ out) {
    __shared__ float Y[4][64][33];   // 33.8 KB

    const int tid = threadIdx.x, bid = blockIdx.x;
    const int wg = ((bid & 7) << 6) | (bid >> 3);      // XCD swizzle: nt uniform per XCD
    const int b = wg & 15, mt = (wg >> 4) & 3, nt = wg >> 6;
    const int lane = tid & 63, wid = tid >> 6;
    const int rank = wid >> 1, wm = wid & 1;
    const int l31 = lane & 31, hi5 = lane >> 5;

    const int slot = bslot[b * 2 + rank];
    const int e = slotE[slot];
    const float wgt = slotW[slot];

    f32x16 acc[4];
    #pragma unroll
    for (int i = 0; i < 4; ++i) acc[i] = (f32x16)(0.f);

    const short* wbase = w2t + (size_t)((e * 4 + (nt >> 1)) * 16) * 4096 + hi5 * 512 + ((nt & 1) * 32 + l31) * 8;
    const uint32_t* abase = s2p + (size_t)slot * 32768 + mt * 256 + wm * 128 + l31;

    short8v b0[4], b1[4];
    uint32_t a0[8], a1[8];

#define G2_LDB(P, B) { const short* wp = wbase + (size_t)(P) * 4096; \
    B[0] = *(const short8v*)(wp);         B[1] = *(const short8v*)(wp + 1024); \
    B[2] = *(const short8v*)(wp + 2048);  B[3] = *(const short8v*)(wp + 3072); }
#define G2_LDA(P, A) { _Pragma("unroll") for (int mf = 0; mf < 4; ++mf) { \
    A[mf * 2]     = abase[(2 * (P)) * 1024 + mf * 32]; \
    A[mf * 2 + 1] = abase[(2 * (P) + 1) * 1024 + mf * 32]; } }
#define G2_MM(A, B) { \
    __builtin_amdgcn_s_setprio(1); \
    _Pragma("unroll") for (int mf = 0; mf < 4; ++mf) \
      _Pragma("unroll") for (int ks = 0; ks < 4; ++ks) { \
        short8v af = unpack8((A[mf * 2 + (ks >> 1)] >> (((ks & 1) * 2 + hi5) * 8)) & 0xffu); \
        acc[mf] = __builtin_amdgcn_mfma_f32_32x32x16_bf16(af, B[ks], acc[mf], 0, 0, 0); } \
    __builtin_amdgcn_s_setprio(0); }

    G2_LDA(0, a0); G2_LDB(0, b0);
    G2_LDA(1, a1); G2_LDB(1, b1);
    G2_MM(a0, b0); SCHED0();
    G2_LDA(2, a0);  G2_LDB(2, b0);  G2_MM(a1, b1); SCHED0();
    G2_LDA(3, a1);  G2_LDB(3, b1);  G2_MM(a0, b0); SCHED0();
    G2_LDA(4, a0);  G2_LDB(4, b0);  G2_MM(a1, b1); SCHED0();
    G2_LDA(5, a1);  G2_LDB(5, b1);  G2_MM(a0, b0); SCHED0();
    G2_LDA(6, a0);  G2_LDB(6, b0);  G2_MM(a1, b1); SCHED0();
    G2_LDA(7, a1);  G2_LDB(7, b1);  G2_MM(a0, b0); SCHED0();
    G2_LDA(8, a0);  G2_LDB(8, b0);  G2_MM(a1, b1); SCHED0();
    G2_LDA(9, a1);  G2_LDB(9, b1);  G2_MM(a0, b0); SCHED0();
    G2_LDA(10, a0); G2_LDB(10, b0); G2_MM(a1, b1); SCHED0();
    G2_LDA(11, a1); G2_LDB(11, b1); G2_MM(a0, b0); SCHED0();
    G2_LDA(12, a0); G2_LDB(12, b0); G2_MM(a1, b1); SCHED0();
    G2_LDA(13, a1); G2_LDB(13, b1); G2_MM(a0, b0); SCHED0();
    G2_LDA(14, a0); G2_LDB(14, b0); G2_MM(a1, b1); SCHED0();
    G2_LDA(15, a1); G2_LDB(15, b1); G2_MM(a0, b0); SCHED0();
    G2_MM(a1, b1);

    // epilogue: rank1 writes wgt*y into Y, rank0 adds, then stream out = x + Y
    {
        int cg = nt * 32 + l31;
        float sc = sc2[e * 256 + cg], sh = sh2[e * 256 + cg];
        if (rank == 1) {
            #pragma unroll
            for (int mf = 0; mf < 4; ++mf)
                #pragma unroll
                for (int q = 0; q < 4; ++q) {
                    int hwl = wm * 32 + mf * 8 + q * 2 + hi5;
                    #pragma unroll
                    for (int t = 0; t < 4; ++t)
                        Y[t][hwl][l31] = wgt * (sc * acc[mf][q * 4 + t] + sh);
                }
        }
        __syncthreads();
        if (rank == 0) {
            #pragma unroll
            for (int mf = 0; mf < 4; ++mf)
                #pragma unroll
                for (int q = 0; q < 4; ++q) {
                    int hwl = wm * 32 + mf * 8 + q * 2 + hi5;
                    #pragma unroll
                    for (int t = 0; t < 4; ++t)
                        Y[t][hwl][l31] += wgt * (sc * acc[mf][q * 4 + t] + sh);
                }
        }
        __syncthreads();
    }
    #pragma unroll
    for (int it = 0; it < 32; ++it) {
        int hwl = tid & 63, t = (tid >> 6) & 3, cl = it;
        size_t oidx = ((size_t)(t * 16 + b) * 256 + nt * 32 + cl) * 256 + mt * 64 + hwl;
        out[oidx] = x[oidx] + Y[t][hwl][cl];
    }
#undef G2_LDB
#undef G2_LDA
#undef G2_MM
}

extern "C" void kernel_launch(void* const* d_in, const int* in_sizes, int n_in,
                              void* d_out, int out_size, void* d_ws, size_t ws_size,
                              hipStream_t stream) {
    const float* x   = (const float*)d_in[0];
    const float* rw  = (const float*)d_in[1];
    const float* rb  = (const float*)d_in[2];
    const float* rg  = (const float*)d_in[3];
    const float* rbt = (const float*)d_in[4];
    const float* rm  = (const float*)d_in[5];
    const float* rv  = (const float*)d_in[6];
    const float* w1  = (const float*)d_in[7];
    const float* b1  = (const float*)d_in[8];
    const float* g1  = (const float*)d_in[9];
    const float* be1 = (const float*)d_in[10];
    const float* m1  = (const float*)d_in[11];
    const float* v1  = (const float*)d_in[12];
    const float* w2  = (const float*)d_in[13];
    const float* b2  = (const float*)d_in[14];
    const float* g2  = (const float*)d_in[15];
    const float* be2 = (const float*)d_in[16];
    const float* m2  = (const float*)d_in[17];
    const float* v2  = (const float*)d_in[18];
    float* out = (float*)d_out;

    char* ws = (char*)d_ws;
    short*    w1c   = (short*)(ws);                    // 8 MiB
    short*    w2t   = (short*)(ws + 8388608);          // 4 MiB
    float*    sc1   = (float*)(ws + 12582912);         // 32 KiB
    float*    sh1   = (float*)(ws + 12615680);         // 32 KiB
    float*    sc2   = (float*)(ws + 12648448);         // 8 KiB
    float*    sh2   = (float*)(ws + 12656640);         // 8 KiB
    float*    xbar  = (float*)(ws + 12664832);         // 16 KiB
    int*      slotE = (int*)  (ws + 12681216);         // 128 B
    float*    slotW = (float*)(ws + 12681344);         // 128 B
    int*      bslot = (int*)  (ws + 12681472);         // 128 B
    uint32_t* s1p   = (uint32_t*)(ws + 12681728);      // 1 MiB
    uint32_t* s2p   = (uint32_t*)(ws + 13730304);      // 4 MiB (total ~17.1 MiB)

    k_prep<<<9248, 256, 0, stream>>>(w1, w2, x, b1, g1, be1, m1, v1, b2, g2, be2, m2, v2,
                                     w1c, w2t, sc1, sh1, sc2, sh2, xbar);
    k_r2  <<<1, 128, 0, stream>>>(xbar, rw, rb, rg, rbt, rm, rv, slotE, slotW, bslot);
    k_lif1<<<dim3(16, 8, 4), 64, 0, stream>>>(x, slotE, bslot, s1p);
    k_g1  <<<1024, 256, 0, stream>>>(s1p, w1c, sc1, sh1, slotE, s2p);
    k_g2  <<<512, 256, 0, stream>>>(s2p, w2t, sc2, sh2, slotE, slotW, bslot, x, out);
}

// Round 8
// 108.059 us; speedup vs baseline: 1.4554x; 1.0395x over previous
//
#include <hip/hip_runtime.h>
#include <hip/hip_bf16.h>
#include <stdint.h>

#define EPSF 1e-5f

typedef short    short4v __attribute__((ext_vector_type(4)));
typedef short    short8v __attribute__((ext_vector_type(8)));
typedef float    f32x16  __attribute__((ext_vector_type(16)));
typedef float    f32x4v  __attribute__((ext_vector_type(4)));
typedef uint32_t u32x4   __attribute__((ext_vector_type(4)));

// dims: T=4, B=16, C=256, H*W=256, Hid=1024, E=8, TOPK=2 -> 32 slots
// x layout (T,B,C,H,W): idx = ((t*16+b)*256+c)*256 + hw ; t-stride = 1048576

static __device__ __forceinline__ short bf16bits(float f) {
    __hip_bfloat16 h = __float2bfloat16(f);
    return *reinterpret_cast<short*>(&h);
}

// unpack 8 spike bits -> 8 bf16 (0.0 / 1.0) entirely in registers
static __device__ __forceinline__ short8v unpack8(uint32_t by) {
    uint32_t lo = ((by & 0xFu) * 0x00204081u) & 0x01010101u;
    uint32_t hi = ((by >> 4)   * 0x00204081u) & 0x01010101u;
    union { short8v s; uint32_t u[4]; } r;
    r.u[0] = __builtin_amdgcn_perm(0u, lo, 0x04010400u) * 0x3F80u;
    r.u[1] = __builtin_amdgcn_perm(0u, lo, 0x04030402u) * 0x3F80u;
    r.u[2] = __builtin_amdgcn_perm(0u, hi, 0x04010400u) * 0x3F80u;
    r.u[3] = __builtin_amdgcn_perm(0u, hi, 0x04030402u) * 0x3F80u;
    return r.s;
}

#define SCHED0() __builtin_amdgcn_sched_barrier(0)

// ---------------- prep: weight convert+tile (unit-major, 4 elem/thread), BN fold, router stage-1 --
// w1c[e][nt4][ks8]{ hi:[u4][n256][8sh] , lo: +8192 sh }   8 MiB   (u = cl>>3)
// w2t[e][nt4][ks16][u8][n64][8sh]                         4 MiB   (u = kl>>3)
__global__ void k_prep(const float* __restrict__ w1, const float* __restrict__ w2,
                       const float* __restrict__ x,
                       const float* __restrict__ b1, const float* __restrict__ g1, const float* __restrict__ be1,
                       const float* __restrict__ m1, const float* __restrict__ v1,
                       const float* __restrict__ b2, const float* __restrict__ g2, const float* __restrict__ be2,
                       const float* __restrict__ m2, const float* __restrict__ v2,
                       short* __restrict__ w1c, short* __restrict__ w2t,
                       float* __restrict__ sc1, float* __restrict__ sh1,
                       float* __restrict__ sc2, float* __restrict__ sh2,
                       float* __restrict__ xbar) {
    int blk = blockIdx.x;
    if (blk < 2048) {
        int i4 = (blk * 256 + threadIdx.x) * 4;
        {   // w1 hi/lo split, unit-major tile: 4 consecutive c share (e,nt,n,ks,u)
            f32x4v f = *(const f32x4v*)(w1 + i4);
            int e = i4 >> 18, o = (i4 >> 8) & 1023, c = i4 & 255;
            int nt = o >> 8, n = o & 255, ks = c >> 5, u = (c & 31) >> 3, j = c & 7;
            size_t base = ((size_t)((e * 4 + nt) * 8 + ks)) * 16384 + u * 2048 + n * 8 + j;
            short4v h4, l4;
            #pragma unroll
            for (int i = 0; i < 4; ++i) {
                __hip_bfloat16 h = __float2bfloat16(f[i]);
                h4[i] = *reinterpret_cast<short*>(&h);
                l4[i] = bf16bits(f[i] - __bfloat162float(h));
            }
            *(short4v*)(w1c + base) = h4;
            *(short4v*)(w1c + base + 8192) = l4;
        }
        {   // w2 bf16, unit-major tile: 4 consecutive k share (e,nt,n,ks,u)
            f32x4v f = *(const f32x4v*)(w2 + i4);
            int e = i4 >> 18, co = (i4 >> 10) & 255, k = i4 & 1023;
            int nt = co >> 6, n = co & 63, ks = k >> 6, u = (k & 63) >> 3, j = k & 7;
            size_t off = ((size_t)((e * 4 + nt) * 16 + ks)) * 4096 + u * 512 + n * 8 + j;
            short4v c4;
            #pragma unroll
            for (int i = 0; i < 4; ++i) c4[i] = bf16bits(f[i]);
            *(short4v*)(w2t + off) = c4;
        }
    } else if (blk < 2080) {
        int idx = (blk - 2048) * 256 + threadIdx.x;   // 0..8191
        {
            float s = g1[idx] / sqrtf(v1[idx] + EPSF);
            sc1[idx] = s;
            sh1[idx] = be1[idx] + s * (b1[idx] - m1[idx]);
        }
        if (idx < 2048) {
            float s = g2[idx] / sqrtf(v2[idx] + EPSF);
            sc2[idx] = s;
            sh2[idx] = be2[idx] + s * (b2[idx] - m2[idx]);
        }
    } else {
        // router stage 1: xbar[b*256+c] = mean over (T,H,W); 4 waves/block, 1 bc each
        int wid = threadIdx.x >> 6, lane = threadIdx.x & 63;
        int bc = (blk - 2080) * 4 + wid;
        const float* xp = x + (size_t)bc * 256;
        float s = 0.f;
        #pragma unroll
        for (int t = 0; t < 4; ++t)
            #pragma unroll
            for (int i = 0; i < 4; ++i)
                s += xp[(size_t)t * 1048576 + i * 64 + lane];
        #pragma unroll
        for (int off = 32; off; off >>= 1) s += __shfl_down(s, off);
        if (lane == 0) xbar[bc] = s * (1.0f / 1024.0f);
    }
}

// ---------------- router stage 2: logits -> top-2 -> expert-sorted 32 slots ----------------
__global__ void k_r2(const float* __restrict__ xbar, const float* __restrict__ rw, const float* __restrict__ rb,
                     const float* __restrict__ rg, const float* __restrict__ rbt,
                     const float* __restrict__ rm, const float* __restrict__ rv,
                     int* __restrict__ slotE, float* __restrict__ slotW, int* __restrict__ bslot) {
    __shared__ float L[16][8];
    __shared__ int   tE[32];
    __shared__ float tW[32];
    int tid = threadIdx.x; // 128
    if (tid < 128) {
        int b = tid >> 3, e = tid & 7;
        float s = 0.f;
        for (int c = 0; c < 256; ++c) s += xbar[b * 256 + c] * rw[e * 256 + c];
        s += rb[e];
        L[b][e] = rg[e] * (s - rm[e]) / sqrtf(rv[e] + EPSF) + rbt[e];
    }
    __syncthreads();
    if (tid < 16) {
        int b = tid;
        float l[8];
        #pragma unroll
        for (int e = 0; e < 8; ++e) l[e] = L[b][e];
        int i1 = 0;
        for (int e = 1; e < 8; ++e) if (l[e] > l[i1]) i1 = e;
        int i2 = (i1 == 0) ? 1 : 0;
        for (int e = 0; e < 8; ++e) { if (e == i1) continue; if (l[e] > l[i2]) i2 = e; }
        float d = l[i2] - l[i1];
        float ed = expf(d);
        tE[b * 2]     = i1; tW[b * 2]     = 1.f / (1.f + ed);
        tE[b * 2 + 1] = i2; tW[b * 2 + 1] = ed / (1.f + ed);
    }
    __syncthreads();
    if (tid == 0) {
        int pos = 0;
        for (int e = 0; e < 8; ++e)
            for (int i = 0; i < 32; ++i)
                if (tE[i] == e) {
                    slotE[pos] = e; slotW[pos] = tW[i];
                    bslot[i] = pos; ++pos;
                }
    }
}

// ---------------- LIF1: 32 routed slots, x read once, ILP-heavy ----------------
// grid (16 b, 8 wq, 4 hwq) x 64 thr. s1p[slot][ks(8)][row(1024)] u32, row = hw*4+t.
__global__ __launch_bounds__(64) void k_lif1(const float* __restrict__ x, const int* __restrict__ slotE,
                                             const int* __restrict__ bslot, uint32_t* __restrict__ s1p) {
    const int b = blockIdx.x, wq = blockIdx.y, hwq = blockIdx.z;
    const int s0 = bslot[b * 2], s1v = bslot[b * 2 + 1];
    const float ta = 1.5f + slotE[s0]  * (2.5f / 7.0f);
    const float tb = 1.5f + slotE[s1v] * (2.5f / 7.0f);
    const int lane = threadIdx.x;
    const int hw = hwq * 64 + lane;
    uint32_t wa[4] = {0, 0, 0, 0}, wb[4] = {0, 0, 0, 0};
    const float* xb = x + (size_t)b * 65536 + (size_t)wq * 8192 + hw;
    #pragma unroll
    for (int j0 = 0; j0 < 32; j0 += 8) {
        float xv[8][4];
        #pragma unroll
        for (int j = 0; j < 8; ++j)
            #pragma unroll
            for (int t = 0; t < 4; ++t)
                xv[j][t] = xb[(size_t)t * 1048576 + (size_t)(j0 + j) * 256];
        #pragma unroll
        for (int j = 0; j < 8; ++j) {
            const uint32_t m = 1u << (j0 + j);
            float v;
            v = xv[j][0] / ta;          if (v >= 1.f) { wa[0] |= m; v = 0.f; }
            v = v + (xv[j][1] - v) / ta; if (v >= 1.f) { wa[1] |= m; v = 0.f; }
            v = v + (xv[j][2] - v) / ta; if (v >= 1.f) { wa[2] |= m; v = 0.f; }
            v = v + (xv[j][3] - v) / ta; if (v >= 1.f) { wa[3] |= m; }
            v = xv[j][0] / tb;          if (v >= 1.f) { wb[0] |= m; v = 0.f; }
            v = v + (xv[j][1] - v) / tb; if (v >= 1.f) { wb[1] |= m; v = 0.f; }
            v = v + (xv[j][2] - v) / tb; if (v >= 1.f) { wb[2] |= m; v = 0.f; }
            v = v + (xv[j][3] - v) / tb; if (v >= 1.f) { wb[3] |= m; }
        }
    }
    *(u32x4*)(s1p + ((size_t)s0  * 8 + wq) * 1024 + hw * 4) = (u32x4){wa[0], wa[1], wa[2], wa[3]};
    *(u32x4*)(s1p + ((size_t)s1v * 8 + wq) * 1024 + hw * 4) = (u32x4){wb[0], wb[1], wb[2], wb[3]};
}

// ================= GEMM1: register-direct, barrier-free. spikes x w1(hi/lo) + BN1 + LIF2 -> s2p ====
// grid 1024 = slot(32) x mrow(8) x nt(4); 256 thr = 4 waves, wave-tile 128 x 64.
// 8 phases of K=32 (hi+lo), B direct from L2 (per-XCD slice ~2MB), reg double-buffer.
__global__ __launch_bounds__(256, 2) void k_g1(const uint32_t* __restrict__ s1p,
                                               const short* __restrict__ w1c,
                                               const float* __restrict__ sc1, const float* __restrict__ sh1,
                                               const int* __restrict__ slotE,
                                               uint32_t* __restrict__ s2p) {
    const int tid = threadIdx.x, bid = blockIdx.x;
    const int wg = ((bid & 7) << 7) | (bid >> 3);      // XCD swizzle: nt uniform per XCD-pair
    const int slot = wg & 31, mrow = (wg >> 5) & 7, nt = wg >> 8;
    const int e = slotE[slot];
    const int lane = tid & 63, wid = tid >> 6;
    const int l31 = lane & 31, hi5 = lane >> 5;

    f32x16 acc[4][2];
    #pragma unroll
    for (int i = 0; i < 4; ++i)
        #pragma unroll
        for (int j = 0; j < 2; ++j) acc[i][j] = (f32x16)(0.f);

    const short* wbase = w1c + (size_t)((e * 4 + nt) * 8) * 16384 + hi5 * 2048 + (wid * 64 + l31) * 8;
    const uint32_t* abase = s1p + (size_t)slot * 8192 + mrow * 128 + l31;

    short8v b0[8], b1[8];
    uint32_t a0[4], a1[4];

#define G1_LDB(P, B) { const short* wp = wbase + (size_t)(P) * 16384; \
    B[0] = *(const short8v*)(wp);                B[1] = *(const short8v*)(wp + 256); \
    B[2] = *(const short8v*)(wp + 4096);         B[3] = *(const short8v*)(wp + 4352); \
    B[4] = *(const short8v*)(wp + 8192);         B[5] = *(const short8v*)(wp + 8448); \
    B[6] = *(const short8v*)(wp + 12288);        B[7] = *(const short8v*)(wp + 12544); }
#define G1_LDA(P, A) { _Pragma("unroll") for (int mf = 0; mf < 4; ++mf) A[mf] = abase[(P) * 1024 + mf * 32]; }
#define G1_MM(A, B) { \
    __builtin_amdgcn_s_setprio(1); \
    _Pragma("unroll") for (int mf = 0; mf < 4; ++mf) \
      _Pragma("unroll") for (int ks = 0; ks < 2; ++ks) { \
        short8v af = unpack8((A[mf] >> ((ks * 2 + hi5) * 8)) & 0xffu); \
        _Pragma("unroll") for (int nf = 0; nf < 2; ++nf) { \
          acc[mf][nf] = __builtin_amdgcn_mfma_f32_32x32x16_bf16(af, B[ks * 2 + nf], acc[mf][nf], 0, 0, 0); \
          acc[mf][nf] = __builtin_amdgcn_mfma_f32_32x32x16_bf16(af, B[4 + ks * 2 + nf], acc[mf][nf], 0, 0, 0); \
        } } \
    __builtin_amdgcn_s_setprio(0); }

    G1_LDA(0, a0); G1_LDB(0, b0);
    G1_LDA(1, a1); G1_LDB(1, b1);
    G1_MM(a0, b0); SCHED0();
    G1_LDA(2, a0); G1_LDB(2, b0); G1_MM(a1, b1); SCHED0();
    G1_LDA(3, a1); G1_LDB(3, b1); G1_MM(a0, b0); SCHED0();
    G1_LDA(4, a0); G1_LDB(4, b0); G1_MM(a1, b1); SCHED0();
    G1_LDA(5, a1); G1_LDB(5, b1); G1_MM(a0, b0); SCHED0();
    G1_LDA(6, a0); G1_LDB(6, b0); G1_MM(a1, b1); SCHED0();
    G1_LDA(7, a1); G1_LDB(7, b1); G1_MM(a0, b0); SCHED0();
    G1_MM(a1, b1);

    // epilogue: BN1 + LIF2 + ballot -> direct global stores (no LDS)
    // C layout 32x32: col=l31, row = 8q + 4*hi5 + t  (reg = q*4 + t)
    const float tau = 1.5f + e * (2.5f / 7.0f);
    #pragma unroll
    for (int mf = 0; mf < 4; ++mf) {
        #pragma unroll
        for (int nf = 0; nf < 2; ++nf) {
            int o = nt * 256 + wid * 64 + nf * 32 + l31;
            float sc = sc1[e * 1024 + o], sh = sh1[e * 1024 + o];
            int w = nt * 8 + wid * 2 + nf;
            #pragma unroll
            for (int q = 0; q < 4; ++q) {
                float v = 0.f;
                #pragma unroll
                for (int t = 0; t < 4; ++t) {
                    float bnv = sc * acc[mf][nf][q * 4 + t] + sh;
                    v = v + (bnv - v) / tau;
                    bool sp = (v >= 1.f);
                    unsigned long long bal = __ballot(sp);
                    if (sp) v = 0.f;
                    if (l31 == 0) {
                        int row = mrow * 128 + mf * 32 + q * 8 + hi5 * 4 + t;
                        s2p[(size_t)(slot * 32 + w) * 1024 + row] = (uint32_t)(bal >> (hi5 * 32));
                    }
                }
            }
        }
    }
#undef G1_LDB
#undef G1_LDA
#undef G1_MM
}

// ================= GEMM2: register-direct, both ranks fused, + BN2 + combine =================
// grid 256 = b(16) x mt(4) x nt(4); 256 thr = 4 waves (rank2 x ms2), wave-tile 128 x 64 (nf=2).
// 16 phases of K=64, deep reg double-buffer. LDS only for the rank-combine Y epilogue.
__global__ __launch_bounds__(256, 2) void k_g2(const uint32_t* __restrict__ s2p,
                                               const short* __restrict__ w2t,
                                               const float* __restrict__ sc2, const float* __restrict__ sh2,
                                               const int* __restrict__ slotE, const float* __restrict__ slotW,
                                               const int* __restrict__ bslot,
                                               const float* __restrict__ x, float* __restrict__ out) {
    __shared__ float Y[4][64][65];   // 66.6 KB

    const int tid = threadIdx.x, bid = blockIdx.x;
    const int wg = ((bid & 7) << 5) | (bid >> 3);      // XCD swizzle (256 blocks)
    const int b = wg & 15, mt = (wg >> 4) & 3, nt = wg >> 6;
    const int lane = tid & 63, wid = tid >> 6;
    const int rank = wid >> 1, ms = wid & 1;
    const int l31 = lane & 31, hi5 = lane >> 5;

    const int slot = bslot[b * 2 + rank];
    const int e = slotE[slot];
    const float wgt = slotW[slot];

    f32x16 acc[4][2];
    #pragma unroll
    for (int i = 0; i < 4; ++i)
        #pragma unroll
        for (int j = 0; j < 2; ++j) acc[i][j] = (f32x16)(0.f);

    const short* wbase = w2t + (size_t)((e * 4 + nt) * 16) * 4096 + hi5 * 512 + l31 * 8;
    const uint32_t* abase = s2p + (size_t)slot * 32768 + (mt * 256 + ms * 128 + l31);

    short8v b0[8], b1[8];
    uint32_t a0[8], a1[8];

#define G2_LDB(P, B) { const short* wp = wbase + (size_t)(P) * 4096; \
    _Pragma("unroll") for (int ks = 0; ks < 4; ++ks) \
      _Pragma("unroll") for (int nf = 0; nf < 2; ++nf) \
        B[ks * 2 + nf] = *(const short8v*)(wp + ks * 1024 + nf * 256); }
#define G2_LDA(P, A) { _Pragma("unroll") for (int mf = 0; mf < 4; ++mf) { \
    A[mf * 2]     = abase[(2 * (P)) * 1024 + mf * 32]; \
    A[mf * 2 + 1] = abase[(2 * (P) + 1) * 1024 + mf * 32]; } }
#define G2_MM(A, B) { \
    __builtin_amdgcn_s_setprio(1); \
    _Pragma("unroll") for (int mf = 0; mf < 4; ++mf) \
      _Pragma("unroll") for (int ks = 0; ks < 4; ++ks) { \
        short8v af = unpack8((A[mf * 2 + (ks >> 1)] >> (((ks & 1) * 2 + hi5) * 8)) & 0xffu); \
        _Pragma("unroll") for (int nf = 0; nf < 2; ++nf) \
          acc[mf][nf] = __builtin_amdgcn_mfma_f32_32x32x16_bf16(af, B[ks * 2 + nf], acc[mf][nf], 0, 0, 0); } \
    __builtin_amdgcn_s_setprio(0); }

    G2_LDA(0, a0); G2_LDB(0, b0);
    G2_LDA(1, a1); G2_LDB(1, b1);
    G2_MM(a0, b0); SCHED0();
    G2_LDA(2, a0);  G2_LDB(2, b0);  G2_MM(a1, b1); SCHED0();
    G2_LDA(3, a1);  G2_LDB(3, b1);  G2_MM(a0, b0); SCHED0();
    G2_LDA(4, a0);  G2_LDB(4, b0);  G2_MM(a1, b1); SCHED0();
    G2_LDA(5, a1);  G2_LDB(5, b1);  G2_MM(a0, b0); SCHED0();
    G2_LDA(6, a0);  G2_LDB(6, b0);  G2_MM(a1, b1); SCHED0();
    G2_LDA(7, a1);  G2_LDB(7, b1);  G2_MM(a0, b0); SCHED0();
    G2_LDA(8, a0);  G2_LDB(8, b0);  G2_MM(a1, b1); SCHED0();
    G2_LDA(9, a1);  G2_LDB(9, b1);  G2_MM(a0, b0); SCHED0();
    G2_LDA(10, a0); G2_LDB(10, b0); G2_MM(a1, b1); SCHED0();
    G2_LDA(11, a1); G2_LDB(11, b1); G2_MM(a0, b0); SCHED0();
    G2_LDA(12, a0); G2_LDB(12, b0); G2_MM(a1, b1); SCHED0();
    G2_LDA(13, a1); G2_LDB(13, b1); G2_MM(a0, b0); SCHED0();
    G2_LDA(14, a0); G2_LDB(14, b0); G2_MM(a1, b1); SCHED0();
    G2_LDA(15, a1); G2_LDB(15, b1); G2_MM(a0, b0); SCHED0();
    G2_MM(a1, b1);

    // epilogue: rank1 writes wgt*y into Y, rank0 adds, then stream out = x + Y
    {
        #pragma unroll
        for (int nf = 0; nf < 2; ++nf) {
            int cl = nf * 32 + l31;
            int cg = nt * 64 + cl;
            float sc = sc2[e * 256 + cg], sh = sh2[e * 256 + cg];
            if (rank == 1) {
                #pragma unroll
                for (int mf = 0; mf < 4; ++mf)
                    #pragma unroll
                    for (int q = 0; q < 4; ++q) {
                        int hwl = ms * 32 + mf * 8 + q * 2 + hi5;
                        #pragma unroll
                        for (int t = 0; t < 4; ++t)
                            Y[t][hwl][cl] = wgt * (sc * acc[mf][nf][q * 4 + t] + sh);
                    }
            }
        }
        __syncthreads();
        #pragma unroll
        for (int nf = 0; nf < 2; ++nf) {
            int cl = nf * 32 + l31;
            int cg = nt * 64 + cl;
            float sc = sc2[e * 256 + cg], sh = sh2[e * 256 + cg];
            if (rank == 0) {
                #pragma unroll
                for (int mf = 0; mf < 4; ++mf)
                    #pragma unroll
                    for (int q = 0; q < 4; ++q) {
                        int hwl = ms * 32 + mf * 8 + q * 2 + hi5;
                        #pragma unroll
                        for (int t = 0; t < 4; ++t)
                            Y[t][hwl][cl] += wgt * (sc * acc[mf][nf][q * 4 + t] + sh);
                    }
            }
        }
        __syncthreads();
    }
    #pragma unroll
    for (int it = 0; it < 64; ++it) {
        int idx = it * 256 + tid;
        int hw = idx & 63, t = (idx >> 6) & 3, cl = idx >> 8;
        size_t oidx = ((size_t)(t * 16 + b) * 256 + nt * 64 + cl) * 256 + mt * 64 + hw;
        out[oidx] = x[oidx] + Y[t][hw][cl];
    }
#undef G2_LDB
#undef G2_LDA
#undef G2_MM
}

extern "C" void kernel_launch(void* const* d_in, const int* in_sizes, int n_in,
                              void* d_out, int out_size, void* d_ws, size_t ws_size,
                              hipStream_t stream) {
    const float* x   = (const float*)d_in[0];
    const float* rw  = (const float*)d_in[1];
    const float* rb  = (const float*)d_in[2];
    const float* rg  = (const float*)d_in[3];
    const float* rbt = (const float*)d_in[4];
    const float* rm  = (const float*)d_in[5];
    const float* rv  = (const float*)d_in[6];
    const float* w1  = (const float*)d_in[7];
    const float* b1  = (const float*)d_in[8];
    const float* g1  = (const float*)d_in[9];
    const float* be1 = (const float*)d_in[10];
    const float* m1  = (const float*)d_in[11];
    const float* v1  = (const float*)d_in[12];
    const float* w2  = (const float*)d_in[13];
    const float* b2  = (const float*)d_in[14];
    const float* g2  = (const float*)d_in[15];
    const float* be2 = (const float*)d_in[16];
    const float* m2  = (const float*)d_in[17];
    const float* v2  = (const float*)d_in[18];
    float* out = (float*)d_out;

    char* ws = (char*)d_ws;
    short*    w1c   = (short*)(ws);                    // 8 MiB
    short*    w2t   = (short*)(ws + 8388608);          // 4 MiB
    float*    sc1   = (float*)(ws + 12582912);         // 32 KiB
    float*    sh1   = (float*)(ws + 12615680);         // 32 KiB
    float*    sc2   = (float*)(ws + 12648448);         // 8 KiB
    float*    sh2   = (float*)(ws + 12656640);         // 8 KiB
    float*    xbar  = (float*)(ws + 12664832);         // 16 KiB
    int*      slotE = (int*)  (ws + 12681216);         // 128 B
    float*    slotW = (float*)(ws + 12681344);         // 128 B
    int*      bslot = (int*)  (ws + 12681472);         // 128 B
    uint32_t* s1p   = (uint32_t*)(ws + 12681728);      // 1 MiB
    uint32_t* s2p   = (uint32_t*)(ws + 13730304);      // 4 MiB (total ~17.1 MiB)

    k_prep<<<3104, 256, 0, stream>>>(w1, w2, x, b1, g1, be1, m1, v1, b2, g2, be2, m2, v2,
                                     w1c, w2t, sc1, sh1, sc2, sh2, xbar);
    k_r2  <<<1, 128, 0, stream>>>(xbar, rw, rb, rg, rbt, rm, rv, slotE, slotW, bslot);
    k_lif1<<<dim3(16, 8, 4), 64, 0, stream>>>(x, slotE, bslot, s1p);
    k_g1  <<<1024, 256, 0, stream>>>(s1p, w1c, sc1, sh1, slotE, s2p);
    k_g2  <<<256, 256, 0, stream>>>(s2p, w2t, sc2, sh2, slotE, slotW, bslot, x, out);
}